// Round 3
// baseline (615.707 us; speedup 1.0000x reference)
//
#include <hip/hip_runtime.h>

typedef unsigned int uint;
typedef unsigned short ushort;
typedef _Float16 f16_t;
typedef f16_t f16x8 __attribute__((ext_vector_type(8)));
typedef ushort ushort8 __attribute__((ext_vector_type(8)));
typedef float f32x4 __attribute__((ext_vector_type(4)));

#define NN 200000
#define EE 600000
#define LL 5
#define GG 2000
#define SCAN_NB 782  // ceil(NN/256); also 200192/256 for the bin-major hist scan

__device__ __forceinline__ ushort f2h(float f) {
  f16_t h = (f16_t)f;
  return __builtin_bit_cast(ushort, h);
}
__device__ __forceinline__ float h2f(ushort u) {
  return (float)__builtin_bit_cast(f16_t, u);
}
__device__ __forceinline__ float hlo(uint u) { return h2f((ushort)(u & 0xFFFFu)); }
__device__ __forceinline__ float hhi(uint u) { return h2f((ushort)(u >> 16)); }
__device__ __forceinline__ f16x8 ld8h(const uint4* p, int idx) {
  uint4 u = p[idx];
  return __builtin_bit_cast(f16x8, u);
}
// h = relu(z*sc+sh) in packed fp16 (v_pk_fma_f16 + v_pk_max_f16)
__device__ __forceinline__ f16x8 bnrelu8(f16x8 u, f16x8 sc, f16x8 sh) {
  f16x8 r = u * sc + sh;
#pragma unroll
  for (int j = 0; j < 8; ++j) r[j] = r[j] > (f16_t)0.f ? r[j] : (f16_t)0.f;
  return r;
}

// ---------------- merged setup: weight swizzle + fp16 tables + xcode + outinit ------
__global__ void k_setup(const float* __restrict__ W1, const float* __restrict__ W2,
                        ushort* __restrict__ w1s, ushort* __restrict__ w2s,
                        const float* __restrict__ ee1, const float* __restrict__ ee2,
                        const float* __restrict__ at1, const float* __restrict__ at2,
                        ushort* __restrict__ tabh, const int* __restrict__ xidx,
                        int* __restrict__ xcode, float* __restrict__ out,
                        const float* __restrict__ bp) {
  int i = blockIdx.x * 256 + threadIdx.x;
  if (i < 40960) {  // weight swizzle, B-frag 16x16x32 order
    int lane = i & 63;
    int f = i >> 6;
    bool isW2 = false;
    if (f >= 320) { f -= 320; isW2 = true; }
    int l = f >> 6, rem = f & 63;
    ushort8 o;
    if (!isW2) {
      int kt = rem >> 4, nt = rem & 15;
      int n = nt * 16 + (lane & 15);
      int kbase = kt * 32 + (lane >> 4) * 8;
#pragma unroll
      for (int j = 0; j < 8; ++j) o[j] = f2h(W1[l * 32768 + (kbase + j) * 256 + n]);
      *(ushort8*)(w1s + f * 512 + lane * 8) = o;
    } else {
      int kt = rem >> 3, nt = rem & 7;
      int n = nt * 16 + (lane & 15);
      int kbase = kt * 32 + (lane >> 4) * 8;
#pragma unroll
      for (int j = 0; j < 8; ++j) o[j] = f2h(W2[l * 32768 + (kbase + j) * 128 + n]);
      *(ushort8*)(w2s + f * 512 + lane * 8) = o;
    }
  }
  if (i < 5760) {  // comb (packed fp16)
    int l = i / 1152, rem = i % 1152;
    int ab = rem >> 7, c = rem & 127;
    int a = ab / 3, b = ab - a * 3;
    tabh[i] = f2h(ee1[(l * 6 + a) * 128 + c] + ee2[(l * 3 + b) * 128 + c]);
  } else if (i < 6400) {  // selfv
    int j = i - 5760;
    int l = j >> 7, c = j & 127;
    tabh[i] = f2h(ee1[(l * 6 + 4) * 128 + c] + ee2[(l * 3 + 0) * 128 + c]);
  } else if (i < 7552) {  // atomc
    int j = i - 6400;
    int ab = j >> 7, c = j & 127;
    int a = ab / 3, b = ab - a * 3;
    tabh[i] = f2h(at1[a * 128 + c] + at2[b * 128 + c]);
  }
  if (i < NN) xcode[i] = xidx[2 * i] * 3 + xidx[2 * i + 1];
  if (i < GG) out[i] = bp[0];
}

// ---------------- CSR build (dst is fixed across layers) ----------------
__global__ void k_count(const int* __restrict__ ei, int* __restrict__ counts) {
  int e = blockIdx.x * 256 + threadIdx.x;
  if (e < EE) atomicAdd(&counts[ei[EE + e]], 1);
}

__global__ void k_scanA(const int* __restrict__ counts, int* __restrict__ rowptr,
                        int* __restrict__ bsums) {
  __shared__ int sd[256];
  int tid = threadIdx.x;
  int g = blockIdx.x * 256 + tid;
  int v = (g < NN) ? counts[g] : 0;
  sd[tid] = v;
  __syncthreads();
  for (int o = 1; o < 256; o <<= 1) {
    int t = (tid >= o) ? sd[tid - o] : 0;
    __syncthreads();
    sd[tid] += t;
    __syncthreads();
  }
  if (g < NN) rowptr[g] = sd[tid] - v;
  if (tid == 255) bsums[blockIdx.x] = sd[tid];
}

__global__ void k_scanB(int* __restrict__ bsums) {
  __shared__ int sd[1024];
  int tid = threadIdx.x;
  int v = (tid < SCAN_NB) ? bsums[tid] : 0;
  sd[tid] = v;
  __syncthreads();
  for (int o = 1; o < 1024; o <<= 1) {
    int t = (tid >= o) ? sd[tid - o] : 0;
    __syncthreads();
    sd[tid] += t;
    __syncthreads();
  }
  if (tid < SCAN_NB) bsums[tid] = sd[tid] - v;
}

__global__ void k_scanC(int* __restrict__ rowptr, const int* __restrict__ bsums) {
  int g = blockIdx.x * 256 + threadIdx.x;
  if (g < NN) rowptr[g] += bsums[blockIdx.x];
  if (g == 0) rowptr[NN] = EE;
}

// pack src (18b) | a9 (4b) | xcode_src (4b)
__global__ void k_fill(const int* __restrict__ ei, const int* __restrict__ ea,
                       const int* __restrict__ xcode, int* __restrict__ cursor,
                       int* __restrict__ eslot) {
  int e = blockIdx.x * 256 + threadIdx.x;
  if (e < EE) {
    int dst = ei[EE + e];
    int src = ei[e];
    int a9 = ea[2 * e] * 3 + ea[2 * e + 1];
    int sc = xcode[src];
    int pos = atomicAdd(&cursor[dst], 1);
    eslot[pos] = src | (a9 << 18) | (sc << 22);
  }
}

// ---------------- degree-balanced node order (privatized counting sort) ----------
// R1 lesson: global atomicAdd-with-return on ~10 hot bins serialized 200k ops
// (k_dfill 869 us at 0% of every pipe). Privatize: per-block LDS histograms ->
// bin-major global array -> flat exclusive scan -> scatter with LDS-rank.
// No global atomics anywhere in the sort.
__global__ void k_hist2(const int* __restrict__ rowptr, int* __restrict__ bhist) {
  __shared__ int h[256];
  int tid = threadIdx.x;
  h[tid] = 0;
  __syncthreads();
  int n = blockIdx.x * 256 + tid;
  if (n < NN) {
    int d = rowptr[n + 1] - rowptr[n];
    if (d > 255) d = 255;
    atomicAdd(&h[d], 1);
  }
  __syncthreads();
  bhist[tid * SCAN_NB + blockIdx.x] = h[tid];  // bin-major
}

// in-place exclusive scan over 782*256 = 200192 entries (exact multiple of 256)
__global__ void k_hscanA(int* __restrict__ data, int* __restrict__ bsums) {
  __shared__ int sd[256];
  int tid = threadIdx.x;
  int g = blockIdx.x * 256 + tid;
  int v = data[g];
  sd[tid] = v;
  __syncthreads();
  for (int o = 1; o < 256; o <<= 1) {
    int t = (tid >= o) ? sd[tid - o] : 0;
    __syncthreads();
    sd[tid] += t;
    __syncthreads();
  }
  data[g] = sd[tid] - v;
  if (tid == 255) bsums[blockIdx.x] = sd[tid];
}

__global__ void k_hscanC(int* __restrict__ data, const int* __restrict__ bsums) {
  int g = blockIdx.x * 256 + threadIdx.x;
  data[g] += bsums[blockIdx.x];
}

// ndesc[pos] = {node, rowstart, rowend, xcode[node]} in degree-sorted order
__global__ void k_dfill2(const int* __restrict__ rowptr, const int* __restrict__ xcode,
                         const int* __restrict__ bpos, int4* __restrict__ ndesc) {
  __shared__ int h[256];
  int tid = threadIdx.x;
  h[tid] = 0;
  __syncthreads();
  int n = blockIdx.x * 256 + tid;
  if (n < NN) {
    int s = rowptr[n], e = rowptr[n + 1];
    int d = e - s;
    if (d > 255) d = 255;
    int r = atomicAdd(&h[d], 1);  // LDS rank within block
    int pos = bpos[d * SCAN_NB + blockIdx.x] + r;
    ndesc[pos] = make_int4(n, s, e, xcode[n]);
  }
}

// ---------------- fused layer: packed-fp16 gather (BN affine inlined), fp16 MLP ----
// zin holds RAW z_{l-1}; per edge: p = relu_pk(z[src]*sc+sh); acc += p + comb.
// Block = 4 waves, 32 DEGREE-SORTED nodes (via ndesc), 16-lane sub-group per node.
// R3: deep prefetch in the gather loop. Degree sort makes trip counts
// wave-uniform, so an unrolled predicated 8-deep prefetch (8 z + 8 comb loads
// in flight per sub-group vs 2 before) has no divergence cost. launch_bounds
// relaxed to (256,4): the prefetch needs ~64 extra VGPRs; (256,5)'s 102-reg cap
// would force spills. Accumulation order per node unchanged (ascending j).
__global__ __launch_bounds__(256, 4) void k_layer(
    const ushort* __restrict__ zin, ushort* __restrict__ zout,
    const int4* __restrict__ ndesc, const ushort* __restrict__ tabh,
    const float* __restrict__ bnscale, const float* __restrict__ bnshift,
    const int* __restrict__ eslot,
    const ushort* __restrict__ w1s, const ushort* __restrict__ w2s,
    const float* __restrict__ b1, const float* __restrict__ b2,
    float* __restrict__ stats, int layer) {
  __shared__ __align__(16) ushort BUF[32 * 264];  // 16,896 B union
  __shared__ int4 ND[32];
  ushort* AGG = BUF;   // 32 x 136 view (gather out / stage-1 in)
  ushort* T1 = BUF;    // 32 x 264 view (stage-1 out / stage-2 in)
  ushort* ldsZ = BUF;  // 32 x 136 view (stage-2 out / store staging)
  const int tid = threadIdx.x;
  const int w = tid >> 6, lane = tid & 63;
  const int ln16 = lane & 15, sub = lane >> 4;
  const int row0 = blockIdx.x * 32;

  if (tid < 32) ND[tid] = ndesc[row0 + tid];
  __syncthreads();

  // ---- gather phase: packed fp16, BN affine inlined ----
  const uint4* combH = (const uint4*)(tabh + (size_t)layer * 1152);
  const uint4* atomH = (const uint4*)(tabh + 6400);
  const uint4* selfH = (const uint4*)(tabh + 5760 + layer * 128);
  const uint4* h4 = (const uint4*)zin;
  f16x8 sf = ld8h(selfH, ln16);
  f16x8 scv = {}, shv = {};
  if (layer > 0) {
    const float* sp = bnscale + (layer - 1) * 128 + ln16 * 8;
    const float* hp = bnshift + (layer - 1) * 128 + ln16 * 8;
#pragma unroll
    for (int j = 0; j < 8; ++j) {
      scv[j] = (f16_t)sp[j];
      shv[j] = (f16_t)hp[j];
    }
  }

#pragma unroll
  for (int grp = 0; grp < 2; ++grp) {
    const int4 nd = ND[w * 8 + grp * 4 + sub];
    const int n = nd.x;
    const int s = nd.y, e = nd.z;
    f16x8 acc;
    if (layer == 0) {
      acc = ld8h(atomH, nd.w * 16 + ln16) + sf;
    } else {
      acc = bnrelu8(ld8h(h4, (size_t)n * 16 + ln16), scv, shv) + sf;
    }
    for (int base = s; base < e; base += 16) {
      int m = e - base;
      if (m > 16) m = 16;
      int slot = (ln16 < m) ? eslot[base + ln16] : 0;
      for (int j0 = 0; j0 < m; j0 += 8) {
        int cnt = m - j0;
        if (cnt > 8) cnt = 8;
        f16x8 pz[8], pc[8];
        // phase 1: issue all loads (8 z + 8 comb outstanding per sub-group)
#pragma unroll
        for (int k = 0; k < 8; ++k) {
          if (k < cnt) {
            int sl = __shfl(slot, sub * 16 + j0 + k, 64);
            if (layer == 0) {
              pz[k] = ld8h(atomH, ((sl >> 22) & 15) * 16 + ln16);
            } else {
              pz[k] = ld8h(h4, (size_t)(sl & 0x3FFFF) * 16 + ln16);
            }
            pc[k] = ld8h(combH, ((sl >> 18) & 15) * 16 + ln16);
          }
        }
        // phase 2: consume in edge order (numerics-identical to x2 version)
#pragma unroll
        for (int k = 0; k < 8; ++k) {
          if (k < cnt) {
            f16x8 p = (layer == 0) ? pz[k] : bnrelu8(pz[k], scv, shv);
            acc += p + pc[k];
          }
        }
      }
    }
    *(uint4*)&AGG[(w * 8 + grp * 4 + sub) * 136 + ln16 * 8] =
        __builtin_bit_cast(uint4, acc);
  }
  __syncthreads();

  // ---- MLP stage 1: acc = AGG @ W1, M=32, fp16; nt in pairs (smaller live set) ----
  const int lm = ln16, q = sub;
  f32x4 acc[2][4] = {};
  const ushort* w1b = w1s + layer * 64 * 512;
#pragma unroll
  for (int kt = 0; kt < 4; ++kt) {
    f16x8 af[2];
#pragma unroll
    for (int mt = 0; mt < 2; ++mt) {
      const ushort* p = AGG + (mt * 16 + lm) * 136 + kt * 32 + q * 8;
      af[mt] = __builtin_bit_cast(f16x8, *(const ushort8*)p);
    }
#pragma unroll
    for (int np = 0; np < 2; ++np) {
      f16x8 bf[2];
#pragma unroll
      for (int ni = 0; ni < 2; ++ni) {
        const ushort* p = w1b + (kt * 16 + w * 4 + np * 2 + ni) * 512 + lane * 8;
        bf[ni] = __builtin_bit_cast(f16x8, *(const ushort8*)p);
      }
#pragma unroll
      for (int mt = 0; mt < 2; ++mt)
#pragma unroll
        for (int ni = 0; ni < 2; ++ni)
          acc[mt][np * 2 + ni] = __builtin_amdgcn_mfma_f32_16x16x32_f16(
              af[mt], bf[ni], acc[mt][np * 2 + ni], 0, 0, 0);
    }
  }
  __syncthreads();  // AGG dead; T1 may now overwrite the union buffer
#pragma unroll
  for (int nt = 0; nt < 4; ++nt) {
    int n = w * 64 + nt * 16 + lm;
    float bias = b1[layer * 256 + n];
#pragma unroll
    for (int mt = 0; mt < 2; ++mt)
#pragma unroll
      for (int r = 0; r < 4; ++r) {
        float v = fmaxf(acc[mt][nt][r] + bias, 0.0f);
        T1[(mt * 16 + q * 4 + r) * 264 + n] = f2h(v);
      }
  }
  __syncthreads();

  // ---- MLP stage 2: z = T1 @ W2 + b2, + BN stats epilogue ----
  f32x4 acc2[2][2] = {};
  const ushort* w2b = w2s + layer * 64 * 512;
#pragma unroll
  for (int kt = 0; kt < 8; ++kt) {
    f16x8 af[2], bf[2];
#pragma unroll
    for (int mt = 0; mt < 2; ++mt) {
      const ushort* p = T1 + (mt * 16 + lm) * 264 + kt * 32 + q * 8;
      af[mt] = __builtin_bit_cast(f16x8, *(const ushort8*)p);
    }
#pragma unroll
    for (int nt = 0; nt < 2; ++nt) {
      const ushort* p = w2b + (kt * 8 + w * 2 + nt) * 512 + lane * 8;
      bf[nt] = __builtin_bit_cast(f16x8, *(const ushort8*)p);
    }
#pragma unroll
    for (int mt = 0; mt < 2; ++mt)
#pragma unroll
      for (int nt = 0; nt < 2; ++nt)
        acc2[mt][nt] = __builtin_amdgcn_mfma_f32_16x16x32_f16(af[mt], bf[nt], acc2[mt][nt], 0, 0, 0);
  }
  __syncthreads();  // T1 dead; ldsZ may now overwrite the union buffer
  float ssum[2], ssq[2];
#pragma unroll
  for (int nt = 0; nt < 2; ++nt) {
    int n = w * 32 + nt * 16 + lm;
    float bias = b2[layer * 128 + n];
    ssum[nt] = 0.f;
    ssq[nt] = 0.f;
#pragma unroll
    for (int mt = 0; mt < 2; ++mt)
#pragma unroll
      for (int r = 0; r < 4; ++r) {
        float v = acc2[mt][nt][r] + bias;
        ldsZ[(mt * 16 + q * 4 + r) * 136 + n] = f2h(v);
        ssum[nt] += v;
        ssq[nt] += v * v;
      }
    ssum[nt] += __shfl_xor(ssum[nt], 16, 64);
    ssum[nt] += __shfl_xor(ssum[nt], 32, 64);
    ssq[nt] += __shfl_xor(ssq[nt], 16, 64);
    ssq[nt] += __shfl_xor(ssq[nt], 32, 64);
  }
  if (lane < 16) {
    int cp = blockIdx.x & 15;
    float* sb = stats + (size_t)(layer * 16 + cp) * 256;
#pragma unroll
    for (int nt = 0; nt < 2; ++nt) {
      int col = w * 32 + nt * 16 + lane;
      atomicAdd(&sb[col], ssum[nt]);
      atomicAdd(&sb[128 + col], ssq[nt]);
    }
  }
  __syncthreads();
  uint* zo = (uint*)zout;
  for (int i = tid; i < 32 * 64; i += 256) {
    int row = i >> 6, cpx = i & 63;
    uint v = *(const uint*)&ldsZ[row * 136 + cpx * 2];
    zo[(size_t)ND[row].x * 64 + cpx] = v;
  }
}

__global__ void k_bnparam(const float* __restrict__ stats, const float* __restrict__ gamma,
                          const float* __restrict__ beta, float* __restrict__ bnscale,
                          float* __restrict__ bnshift, int layer) {
  int c = threadIdx.x;
  float s = 0.f, qv = 0.f;
  for (int cp = 0; cp < 16; ++cp) {
    const float* sb = stats + (size_t)(layer * 16 + cp) * 256;
    s += sb[c];
    qv += sb[128 + c];
  }
  float mu = s * (1.0f / NN);
  float var = qv * (1.0f / NN) - mu * mu;
  float sc = gamma[layer * 128 + c] * rsqrtf(var + 1e-5f);
  bnscale[layer * 128 + c] = sc;
  bnshift[layer * 128 + c] = beta[layer * 128 + c] - mu * sc;
}

// ---------------- pooling with segmented running sum (batch sorted) ----------------
__global__ __launch_bounds__(256) void k_pool(const ushort* __restrict__ z,
                                              const float* __restrict__ bnscale,
                                              const float* __restrict__ bnshift,
                                              const int* __restrict__ batch,
                                              const float* __restrict__ Wp,
                                              float* __restrict__ out) {
  const int tid = threadIdx.x;
  const int w = tid >> 6, lane = tid & 63;
  const int nb = blockIdx.x * 64 + w * 16;
  float2 wp = ((const float2*)Wp)[lane];
  float2 scv = ((const float2*)(bnscale + 4 * 128))[lane];
  float2 shv = ((const float2*)(bnshift + 4 * 128))[lane];
  const uint* z32 = (const uint*)z;
  int bb = (lane < 16) ? batch[nb + lane] : 0;
  int curb = __shfl(bb, 0);
  float run = 0.f;
#pragma unroll
  for (int i = 0; i < 16; ++i) {
    int b = __shfl(bb, i);
    uint u = z32[(size_t)(nb + i) * 64 + lane];
    float dot = fmaf(hlo(u), scv.x, shv.x) * wp.x + fmaf(hhi(u), scv.y, shv.y) * wp.y;
#pragma unroll
    for (int off = 32; off > 0; off >>= 1) dot += __shfl_xor(dot, off, 64);
    if (b != curb) {
      if (lane == 0) atomicAdd(&out[curb], run);
      run = 0.f;
      curb = b;
    }
    run += dot;
  }
  if (lane == 0) atomicAdd(&out[curb], run);
}

extern "C" void kernel_launch(void* const* d_in, const int* in_sizes, int n_in,
                              void* d_out, int out_size, void* d_ws, size_t ws_size,
                              hipStream_t stream) {
  (void)in_sizes; (void)n_in; (void)out_size; (void)ws_size;
  const int* xidx = (const int*)d_in[0];
  const int* eidx = (const int*)d_in[1];
  const int* eattr = (const int*)d_in[2];
  const int* batch = (const int*)d_in[3];
  const float* at1 = (const float*)d_in[4];
  const float* at2 = (const float*)d_in[5];
  const float* ee1 = (const float*)d_in[6];
  const float* ee2 = (const float*)d_in[7];
  const float* W1 = (const float*)d_in[8];
  const float* b1 = (const float*)d_in[9];
  const float* W2 = (const float*)d_in[10];
  const float* b2 = (const float*)d_in[11];
  const float* gamma = (const float*)d_in[12];
  const float* beta = (const float*)d_in[13];
  const float* Wp = (const float*)d_in[14];
  const float* bp = (const float*)d_in[15];
  float* out = (float*)d_out;

  char* ws = (char*)d_ws;
  size_t off = 0;
  auto alloc = [&](size_t bytes) -> void* {
    void* p = ws + off;
    off = (off + bytes + 255) & ~(size_t)255;
    return p;
  };
  ushort* bufA = (ushort*)alloc((size_t)NN * 128 * 2);
  ushort* bufB = (ushort*)alloc((size_t)NN * 128 * 2);
  ushort* w1s = (ushort*)alloc(320 * 512 * 2);
  ushort* w2s = (ushort*)alloc(320 * 512 * 2);
  int* rowptr = (int*)alloc((NN + 1) * 4);
  int* cursor = (int*)alloc((size_t)NN * 4);
  int* eslot = (int*)alloc((size_t)EE * 4);
  int* bsums = (int*)alloc(1024 * 4);
  ushort* tabh = (ushort*)alloc(7552 * 2);
  int* xcode = (int*)alloc((size_t)NN * 4);
  float* stats = (float*)alloc((size_t)LL * 16 * 256 * 4);
  float* bnscale = (float*)alloc(LL * 128 * 4);
  float* bnshift = (float*)alloc(LL * 128 * 4);
  int* bhist = (int*)alloc((size_t)SCAN_NB * 256 * 4);
  int* bsums2 = (int*)alloc(1024 * 4);
  int4* ndesc = (int4*)alloc((size_t)NN * 16);

  hipMemsetAsync(cursor, 0, (size_t)NN * 4, stream);
  hipMemsetAsync(stats, 0, (size_t)LL * 16 * 256 * 4, stream);
  k_setup<<<SCAN_NB, 256, 0, stream>>>(W1, W2, w1s, w2s, ee1, ee2, at1, at2, tabh, xidx,
                                       xcode, out, bp);
  k_count<<<(EE + 255) / 256, 256, 0, stream>>>(eidx, cursor);
  k_scanA<<<SCAN_NB, 256, 0, stream>>>(cursor, rowptr, bsums);
  k_scanB<<<1, 1024, 0, stream>>>(bsums);
  k_scanC<<<SCAN_NB, 256, 0, stream>>>(rowptr, bsums);
  hipMemcpyAsync(cursor, rowptr, (size_t)NN * 4, hipMemcpyDeviceToDevice, stream);
  k_fill<<<(EE + 255) / 256, 256, 0, stream>>>(eidx, eattr, xcode, cursor, eslot);
  // degree-balanced node ordering (privatized counting sort, no global atomics)
  k_hist2<<<SCAN_NB, 256, 0, stream>>>(rowptr, bhist);
  k_hscanA<<<SCAN_NB, 256, 0, stream>>>(bhist, bsums2);
  k_scanB<<<1, 1024, 0, stream>>>(bsums2);
  k_hscanC<<<SCAN_NB, 256, 0, stream>>>(bhist, bsums2);
  k_dfill2<<<SCAN_NB, 256, 0, stream>>>(rowptr, xcode, bhist, ndesc);

  for (int l = 0; l < LL; ++l) {
    ushort* zo = (l & 1) ? bufB : bufA;
    const ushort* zi = (l & 1) ? bufA : bufB;  // raw z_{l-1}; unused for l==0
    k_layer<<<NN / 32, 256, 0, stream>>>((l == 0) ? bufA : zi, zo, ndesc, tabh, bnscale,
                                         bnshift, eslot, w1s, w2s, b1, b2,
                                         stats, l);
    k_bnparam<<<1, 128, 0, stream>>>(stats, gamma, beta, bnscale, bnshift, l);
  }
  k_pool<<<NN / 64, 256, 0, stream>>>(bufA, bnscale, bnshift, batch, Wp, out);
}

// Round 4
// 555.339 us; speedup vs baseline: 1.1087x; 1.1087x over previous
//
#include <hip/hip_runtime.h>

typedef unsigned int uint;
typedef unsigned short ushort;
typedef _Float16 f16_t;
typedef f16_t f16x8 __attribute__((ext_vector_type(8)));
typedef ushort ushort8 __attribute__((ext_vector_type(8)));
typedef float f32x4 __attribute__((ext_vector_type(4)));

#define NN 200000
#define EE 600000
#define LL 5
#define GG 2000
#define SCAN_NB 782  // ceil(NN/256); also 200192/256 for the bin-major hist scan

__device__ __forceinline__ ushort f2h(float f) {
  f16_t h = (f16_t)f;
  return __builtin_bit_cast(ushort, h);
}
__device__ __forceinline__ float h2f(ushort u) {
  return (float)__builtin_bit_cast(f16_t, u);
}
__device__ __forceinline__ float hlo(uint u) { return h2f((ushort)(u & 0xFFFFu)); }
__device__ __forceinline__ float hhi(uint u) { return h2f((ushort)(u >> 16)); }
__device__ __forceinline__ f16x8 ld8h(const uint4* p, int idx) {
  uint4 u = p[idx];
  return __builtin_bit_cast(f16x8, u);
}
// h = relu(z*sc+sh) in packed fp16 (v_pk_fma_f16 + v_pk_max_f16)
__device__ __forceinline__ f16x8 bnrelu8(f16x8 u, f16x8 sc, f16x8 sh) {
  f16x8 r = u * sc + sh;
#pragma unroll
  for (int j = 0; j < 8; ++j) r[j] = r[j] > (f16_t)0.f ? r[j] : (f16_t)0.f;
  return r;
}

// ---------------- merged setup: weight swizzle + fp16 tables + xcode + outinit ------
__global__ void k_setup(const float* __restrict__ W1, const float* __restrict__ W2,
                        ushort* __restrict__ w1s, ushort* __restrict__ w2s,
                        const float* __restrict__ ee1, const float* __restrict__ ee2,
                        const float* __restrict__ at1, const float* __restrict__ at2,
                        ushort* __restrict__ tabh, const int* __restrict__ xidx,
                        int* __restrict__ xcode, float* __restrict__ out,
                        const float* __restrict__ bp) {
  int i = blockIdx.x * 256 + threadIdx.x;
  if (i < 40960) {  // weight swizzle, B-frag 16x16x32 order
    int lane = i & 63;
    int f = i >> 6;
    bool isW2 = false;
    if (f >= 320) { f -= 320; isW2 = true; }
    int l = f >> 6, rem = f & 63;
    ushort8 o;
    if (!isW2) {
      int kt = rem >> 4, nt = rem & 15;
      int n = nt * 16 + (lane & 15);
      int kbase = kt * 32 + (lane >> 4) * 8;
#pragma unroll
      for (int j = 0; j < 8; ++j) o[j] = f2h(W1[l * 32768 + (kbase + j) * 256 + n]);
      *(ushort8*)(w1s + f * 512 + lane * 8) = o;
    } else {
      int kt = rem >> 3, nt = rem & 7;
      int n = nt * 16 + (lane & 15);
      int kbase = kt * 32 + (lane >> 4) * 8;
#pragma unroll
      for (int j = 0; j < 8; ++j) o[j] = f2h(W2[l * 32768 + (kbase + j) * 128 + n]);
      *(ushort8*)(w2s + f * 512 + lane * 8) = o;
    }
  }
  if (i < 5760) {  // comb (packed fp16)
    int l = i / 1152, rem = i % 1152;
    int ab = rem >> 7, c = rem & 127;
    int a = ab / 3, b = ab - a * 3;
    tabh[i] = f2h(ee1[(l * 6 + a) * 128 + c] + ee2[(l * 3 + b) * 128 + c]);
  } else if (i < 6400) {  // selfv
    int j = i - 5760;
    int l = j >> 7, c = j & 127;
    tabh[i] = f2h(ee1[(l * 6 + 4) * 128 + c] + ee2[(l * 3 + 0) * 128 + c]);
  } else if (i < 7552) {  // atomc
    int j = i - 6400;
    int ab = j >> 7, c = j & 127;
    int a = ab / 3, b = ab - a * 3;
    tabh[i] = f2h(at1[a * 128 + c] + at2[b * 128 + c]);
  }
  if (i < NN) xcode[i] = xidx[2 * i] * 3 + xidx[2 * i + 1];
  if (i < GG) out[i] = bp[0];
}

// ---------------- CSR build (dst is fixed across layers) ----------------
__global__ void k_count(const int* __restrict__ ei, int* __restrict__ counts) {
  int e = blockIdx.x * 256 + threadIdx.x;
  if (e < EE) atomicAdd(&counts[ei[EE + e]], 1);
}

__global__ void k_scanA(const int* __restrict__ counts, int* __restrict__ rowptr,
                        int* __restrict__ bsums) {
  __shared__ int sd[256];
  int tid = threadIdx.x;
  int g = blockIdx.x * 256 + tid;
  int v = (g < NN) ? counts[g] : 0;
  sd[tid] = v;
  __syncthreads();
  for (int o = 1; o < 256; o <<= 1) {
    int t = (tid >= o) ? sd[tid - o] : 0;
    __syncthreads();
    sd[tid] += t;
    __syncthreads();
  }
  if (g < NN) rowptr[g] = sd[tid] - v;
  if (tid == 255) bsums[blockIdx.x] = sd[tid];
}

__global__ void k_scanB(int* __restrict__ bsums) {
  __shared__ int sd[1024];
  int tid = threadIdx.x;
  int v = (tid < SCAN_NB) ? bsums[tid] : 0;
  sd[tid] = v;
  __syncthreads();
  for (int o = 1; o < 1024; o <<= 1) {
    int t = (tid >= o) ? sd[tid - o] : 0;
    __syncthreads();
    sd[tid] += t;
    __syncthreads();
  }
  if (tid < SCAN_NB) bsums[tid] = sd[tid] - v;
}

__global__ void k_scanC(int* __restrict__ rowptr, const int* __restrict__ bsums) {
  int g = blockIdx.x * 256 + threadIdx.x;
  if (g < NN) rowptr[g] += bsums[blockIdx.x];
  if (g == 0) rowptr[NN] = EE;
}

// pack src (18b) | a9 (4b) | xcode_src (4b)
__global__ void k_fill(const int* __restrict__ ei, const int* __restrict__ ea,
                       const int* __restrict__ xcode, int* __restrict__ cursor,
                       int* __restrict__ eslot) {
  int e = blockIdx.x * 256 + threadIdx.x;
  if (e < EE) {
    int dst = ei[EE + e];
    int src = ei[e];
    int a9 = ea[2 * e] * 3 + ea[2 * e + 1];
    int sc = xcode[src];
    int pos = atomicAdd(&cursor[dst], 1);
    eslot[pos] = src | (a9 << 18) | (sc << 22);
  }
}

// ---------------- degree-balanced node order (privatized counting sort) ----------
// R1 lesson: global atomicAdd-with-return on ~10 hot bins serialized 200k ops
// (k_dfill 869 us at 0% of every pipe). Privatize: per-block LDS histograms ->
// bin-major global array -> flat exclusive scan -> scatter with LDS-rank.
// No global atomics anywhere in the sort.
__global__ void k_hist2(const int* __restrict__ rowptr, int* __restrict__ bhist) {
  __shared__ int h[256];
  int tid = threadIdx.x;
  h[tid] = 0;
  __syncthreads();
  int n = blockIdx.x * 256 + tid;
  if (n < NN) {
    int d = rowptr[n + 1] - rowptr[n];
    if (d > 255) d = 255;
    atomicAdd(&h[d], 1);
  }
  __syncthreads();
  bhist[tid * SCAN_NB + blockIdx.x] = h[tid];  // bin-major
}

// in-place exclusive scan over 782*256 = 200192 entries (exact multiple of 256)
__global__ void k_hscanA(int* __restrict__ data, int* __restrict__ bsums) {
  __shared__ int sd[256];
  int tid = threadIdx.x;
  int g = blockIdx.x * 256 + tid;
  int v = data[g];
  sd[tid] = v;
  __syncthreads();
  for (int o = 1; o < 256; o <<= 1) {
    int t = (tid >= o) ? sd[tid - o] : 0;
    __syncthreads();
    sd[tid] += t;
    __syncthreads();
  }
  data[g] = sd[tid] - v;
  if (tid == 255) bsums[blockIdx.x] = sd[tid];
}

__global__ void k_hscanC(int* __restrict__ data, const int* __restrict__ bsums) {
  int g = blockIdx.x * 256 + threadIdx.x;
  data[g] += bsums[blockIdx.x];
}

// ndesc[pos] = {node, rowstart, rowend, xcode[node]} in degree-sorted order
__global__ void k_dfill2(const int* __restrict__ rowptr, const int* __restrict__ xcode,
                         const int* __restrict__ bpos, int4* __restrict__ ndesc) {
  __shared__ int h[256];
  int tid = threadIdx.x;
  h[tid] = 0;
  __syncthreads();
  int n = blockIdx.x * 256 + tid;
  if (n < NN) {
    int s = rowptr[n], e = rowptr[n + 1];
    int d = e - s;
    if (d > 255) d = 255;
    int r = atomicAdd(&h[d], 1);  // LDS rank within block
    int pos = bpos[d * SCAN_NB + blockIdx.x] + r;
    ndesc[pos] = make_int4(n, s, e, xcode[n]);
  }
}

// ---------------- fused layer: packed-fp16 gather (BN affine inlined), fp16 MLP ----
// zin holds RAW z_{l-1}; per edge: p = relu_pk(z[src]*sc+sh); acc += p + comb.
// Block = 4 waves, 32 DEGREE-SORTED nodes (via ndesc), 16-lane sub-group per node.
// R4: branchless x4 edge batching. R3 lesson: per-load `if (k<cnt)` predication
// puts each load in its own basic block -> compiler never batches issues (VGPR
// stayed 56, regressed to 94us). Fix: full groups of 4 with ZERO predication
// (4 shfl -> 4 z loads -> 4 comb loads -> ordered consume) + scalar remainder.
// Degree sort makes trip counts wave-uniform so the remainder rarely diverges.
// launch_bounds back to (256,5): live set ~76-90 VGPR fits the ~102 cap.
__global__ __launch_bounds__(256, 5) void k_layer(
    const ushort* __restrict__ zin, ushort* __restrict__ zout,
    const int4* __restrict__ ndesc, const ushort* __restrict__ tabh,
    const float* __restrict__ bnscale, const float* __restrict__ bnshift,
    const int* __restrict__ eslot,
    const ushort* __restrict__ w1s, const ushort* __restrict__ w2s,
    const float* __restrict__ b1, const float* __restrict__ b2,
    float* __restrict__ stats, int layer) {
  __shared__ __align__(16) ushort BUF[32 * 264];  // 16,896 B union
  __shared__ int4 ND[32];
  ushort* AGG = BUF;   // 32 x 136 view (gather out / stage-1 in)
  ushort* T1 = BUF;    // 32 x 264 view (stage-1 out / stage-2 in)
  ushort* ldsZ = BUF;  // 32 x 136 view (stage-2 out / store staging)
  const int tid = threadIdx.x;
  const int w = tid >> 6, lane = tid & 63;
  const int ln16 = lane & 15, sub = lane >> 4;
  const int row0 = blockIdx.x * 32;

  if (tid < 32) ND[tid] = ndesc[row0 + tid];
  __syncthreads();

  // ---- gather phase: packed fp16, BN affine inlined ----
  const uint4* combH = (const uint4*)(tabh + (size_t)layer * 1152);
  const uint4* atomH = (const uint4*)(tabh + 6400);
  const uint4* selfH = (const uint4*)(tabh + 5760 + layer * 128);
  const uint4* h4 = (const uint4*)zin;
  f16x8 sf = ld8h(selfH, ln16);
  f16x8 scv = {}, shv = {};
  if (layer > 0) {
    const float* sp = bnscale + (layer - 1) * 128 + ln16 * 8;
    const float* hp = bnshift + (layer - 1) * 128 + ln16 * 8;
#pragma unroll
    for (int j = 0; j < 8; ++j) {
      scv[j] = (f16_t)sp[j];
      shv[j] = (f16_t)hp[j];
    }
  }

#pragma unroll
  for (int grp = 0; grp < 2; ++grp) {
    const int4 nd = ND[w * 8 + grp * 4 + sub];
    const int n = nd.x;
    const int s = nd.y, e = nd.z;
    f16x8 acc;
    if (layer == 0) {
      acc = ld8h(atomH, nd.w * 16 + ln16) + sf;
    } else {
      acc = bnrelu8(ld8h(h4, (size_t)n * 16 + ln16), scv, shv) + sf;
    }
    for (int base = s; base < e; base += 16) {
      int m = e - base;
      if (m > 16) m = 16;
      int slot = (ln16 < m) ? eslot[base + ln16] : 0;
      int jfull = m & ~3;
      int j = 0;
      for (; j < jfull; j += 4) {
        // branchless depth-4 batch: all shfls, then all loads, then consume
        int sl0 = __shfl(slot, sub * 16 + j + 0, 64);
        int sl1 = __shfl(slot, sub * 16 + j + 1, 64);
        int sl2 = __shfl(slot, sub * 16 + j + 2, 64);
        int sl3 = __shfl(slot, sub * 16 + j + 3, 64);
        f16x8 p0, p1, p2, p3;
        if (layer == 0) {
          p0 = ld8h(atomH, ((sl0 >> 22) & 15) * 16 + ln16);
          p1 = ld8h(atomH, ((sl1 >> 22) & 15) * 16 + ln16);
          p2 = ld8h(atomH, ((sl2 >> 22) & 15) * 16 + ln16);
          p3 = ld8h(atomH, ((sl3 >> 22) & 15) * 16 + ln16);
        } else {
          p0 = ld8h(h4, (size_t)(sl0 & 0x3FFFF) * 16 + ln16);
          p1 = ld8h(h4, (size_t)(sl1 & 0x3FFFF) * 16 + ln16);
          p2 = ld8h(h4, (size_t)(sl2 & 0x3FFFF) * 16 + ln16);
          p3 = ld8h(h4, (size_t)(sl3 & 0x3FFFF) * 16 + ln16);
        }
        f16x8 c0 = ld8h(combH, ((sl0 >> 18) & 15) * 16 + ln16);
        f16x8 c1 = ld8h(combH, ((sl1 >> 18) & 15) * 16 + ln16);
        f16x8 c2 = ld8h(combH, ((sl2 >> 18) & 15) * 16 + ln16);
        f16x8 c3 = ld8h(combH, ((sl3 >> 18) & 15) * 16 + ln16);
        if (layer != 0) {
          p0 = bnrelu8(p0, scv, shv);
          p1 = bnrelu8(p1, scv, shv);
          p2 = bnrelu8(p2, scv, shv);
          p3 = bnrelu8(p3, scv, shv);
        }
        acc += p0 + c0;
        acc += p1 + c1;
        acc += p2 + c2;
        acc += p3 + c3;
      }
      for (; j < m; ++j) {
        int sl = __shfl(slot, sub * 16 + j, 64);
        f16x8 p0;
        if (layer == 0) {
          p0 = ld8h(atomH, ((sl >> 22) & 15) * 16 + ln16);
        } else {
          p0 = bnrelu8(ld8h(h4, (size_t)(sl & 0x3FFFF) * 16 + ln16), scv, shv);
        }
        f16x8 c0 = ld8h(combH, ((sl >> 18) & 15) * 16 + ln16);
        acc += p0 + c0;
      }
    }
    *(uint4*)&AGG[(w * 8 + grp * 4 + sub) * 136 + ln16 * 8] =
        __builtin_bit_cast(uint4, acc);
  }
  __syncthreads();

  // ---- MLP stage 1: acc = AGG @ W1, M=32, fp16; nt in pairs (smaller live set) ----
  const int lm = ln16, q = sub;
  f32x4 acc[2][4] = {};
  const ushort* w1b = w1s + layer * 64 * 512;
#pragma unroll
  for (int kt = 0; kt < 4; ++kt) {
    f16x8 af[2];
#pragma unroll
    for (int mt = 0; mt < 2; ++mt) {
      const ushort* p = AGG + (mt * 16 + lm) * 136 + kt * 32 + q * 8;
      af[mt] = __builtin_bit_cast(f16x8, *(const ushort8*)p);
    }
#pragma unroll
    for (int np = 0; np < 2; ++np) {
      f16x8 bf[2];
#pragma unroll
      for (int ni = 0; ni < 2; ++ni) {
        const ushort* p = w1b + (kt * 16 + w * 4 + np * 2 + ni) * 512 + lane * 8;
        bf[ni] = __builtin_bit_cast(f16x8, *(const ushort8*)p);
      }
#pragma unroll
      for (int mt = 0; mt < 2; ++mt)
#pragma unroll
        for (int ni = 0; ni < 2; ++ni)
          acc[mt][np * 2 + ni] = __builtin_amdgcn_mfma_f32_16x16x32_f16(
              af[mt], bf[ni], acc[mt][np * 2 + ni], 0, 0, 0);
    }
  }
  __syncthreads();  // AGG dead; T1 may now overwrite the union buffer
#pragma unroll
  for (int nt = 0; nt < 4; ++nt) {
    int n = w * 64 + nt * 16 + lm;
    float bias = b1[layer * 256 + n];
#pragma unroll
    for (int mt = 0; mt < 2; ++mt)
#pragma unroll
      for (int r = 0; r < 4; ++r) {
        float v = fmaxf(acc[mt][nt][r] + bias, 0.0f);
        T1[(mt * 16 + q * 4 + r) * 264 + n] = f2h(v);
      }
  }
  __syncthreads();

  // ---- MLP stage 2: z = T1 @ W2 + b2, + BN stats epilogue ----
  f32x4 acc2[2][2] = {};
  const ushort* w2b = w2s + layer * 64 * 512;
#pragma unroll
  for (int kt = 0; kt < 8; ++kt) {
    f16x8 af[2], bf[2];
#pragma unroll
    for (int mt = 0; mt < 2; ++mt) {
      const ushort* p = T1 + (mt * 16 + lm) * 264 + kt * 32 + q * 8;
      af[mt] = __builtin_bit_cast(f16x8, *(const ushort8*)p);
    }
#pragma unroll
    for (int nt = 0; nt < 2; ++nt) {
      const ushort* p = w2b + (kt * 8 + w * 2 + nt) * 512 + lane * 8;
      bf[nt] = __builtin_bit_cast(f16x8, *(const ushort8*)p);
    }
#pragma unroll
    for (int mt = 0; mt < 2; ++mt)
#pragma unroll
      for (int nt = 0; nt < 2; ++nt)
        acc2[mt][nt] = __builtin_amdgcn_mfma_f32_16x16x32_f16(af[mt], bf[nt], acc2[mt][nt], 0, 0, 0);
  }
  __syncthreads();  // T1 dead; ldsZ may now overwrite the union buffer
  float ssum[2], ssq[2];
#pragma unroll
  for (int nt = 0; nt < 2; ++nt) {
    int n = w * 32 + nt * 16 + lm;
    float bias = b2[layer * 128 + n];
    ssum[nt] = 0.f;
    ssq[nt] = 0.f;
#pragma unroll
    for (int mt = 0; mt < 2; ++mt)
#pragma unroll
      for (int r = 0; r < 4; ++r) {
        float v = acc2[mt][nt][r] + bias;
        ldsZ[(mt * 16 + q * 4 + r) * 136 + n] = f2h(v);
        ssum[nt] += v;
        ssq[nt] += v * v;
      }
    ssum[nt] += __shfl_xor(ssum[nt], 16, 64);
    ssum[nt] += __shfl_xor(ssum[nt], 32, 64);
    ssq[nt] += __shfl_xor(ssq[nt], 16, 64);
    ssq[nt] += __shfl_xor(ssq[nt], 32, 64);
  }
  if (lane < 16) {
    int cp = blockIdx.x & 15;
    float* sb = stats + (size_t)(layer * 16 + cp) * 256;
#pragma unroll
    for (int nt = 0; nt < 2; ++nt) {
      int col = w * 32 + nt * 16 + lane;
      atomicAdd(&sb[col], ssum[nt]);
      atomicAdd(&sb[128 + col], ssq[nt]);
    }
  }
  __syncthreads();
  uint* zo = (uint*)zout;
  for (int i = tid; i < 32 * 64; i += 256) {
    int row = i >> 6, cpx = i & 63;
    uint v = *(const uint*)&ldsZ[row * 136 + cpx * 2];
    zo[(size_t)ND[row].x * 64 + cpx] = v;
  }
}

__global__ void k_bnparam(const float* __restrict__ stats, const float* __restrict__ gamma,
                          const float* __restrict__ beta, float* __restrict__ bnscale,
                          float* __restrict__ bnshift, int layer) {
  int c = threadIdx.x;
  float s = 0.f, qv = 0.f;
  for (int cp = 0; cp < 16; ++cp) {
    const float* sb = stats + (size_t)(layer * 16 + cp) * 256;
    s += sb[c];
    qv += sb[128 + c];
  }
  float mu = s * (1.0f / NN);
  float var = qv * (1.0f / NN) - mu * mu;
  float sc = gamma[layer * 128 + c] * rsqrtf(var + 1e-5f);
  bnscale[layer * 128 + c] = sc;
  bnshift[layer * 128 + c] = beta[layer * 128 + c] - mu * sc;
}

// ---------------- pooling with segmented running sum (batch sorted) ----------------
__global__ __launch_bounds__(256) void k_pool(const ushort* __restrict__ z,
                                              const float* __restrict__ bnscale,
                                              const float* __restrict__ bnshift,
                                              const int* __restrict__ batch,
                                              const float* __restrict__ Wp,
                                              float* __restrict__ out) {
  const int tid = threadIdx.x;
  const int w = tid >> 6, lane = tid & 63;
  const int nb = blockIdx.x * 64 + w * 16;
  float2 wp = ((const float2*)Wp)[lane];
  float2 scv = ((const float2*)(bnscale + 4 * 128))[lane];
  float2 shv = ((const float2*)(bnshift + 4 * 128))[lane];
  const uint* z32 = (const uint*)z;
  int bb = (lane < 16) ? batch[nb + lane] : 0;
  int curb = __shfl(bb, 0);
  float run = 0.f;
#pragma unroll
  for (int i = 0; i < 16; ++i) {
    int b = __shfl(bb, i);
    uint u = z32[(size_t)(nb + i) * 64 + lane];
    float dot = fmaf(hlo(u), scv.x, shv.x) * wp.x + fmaf(hhi(u), scv.y, shv.y) * wp.y;
#pragma unroll
    for (int off = 32; off > 0; off >>= 1) dot += __shfl_xor(dot, off, 64);
    if (b != curb) {
      if (lane == 0) atomicAdd(&out[curb], run);
      run = 0.f;
      curb = b;
    }
    run += dot;
  }
  if (lane == 0) atomicAdd(&out[curb], run);
}

extern "C" void kernel_launch(void* const* d_in, const int* in_sizes, int n_in,
                              void* d_out, int out_size, void* d_ws, size_t ws_size,
                              hipStream_t stream) {
  (void)in_sizes; (void)n_in; (void)out_size; (void)ws_size;
  const int* xidx = (const int*)d_in[0];
  const int* eidx = (const int*)d_in[1];
  const int* eattr = (const int*)d_in[2];
  const int* batch = (const int*)d_in[3];
  const float* at1 = (const float*)d_in[4];
  const float* at2 = (const float*)d_in[5];
  const float* ee1 = (const float*)d_in[6];
  const float* ee2 = (const float*)d_in[7];
  const float* W1 = (const float*)d_in[8];
  const float* b1 = (const float*)d_in[9];
  const float* W2 = (const float*)d_in[10];
  const float* b2 = (const float*)d_in[11];
  const float* gamma = (const float*)d_in[12];
  const float* beta = (const float*)d_in[13];
  const float* Wp = (const float*)d_in[14];
  const float* bp = (const float*)d_in[15];
  float* out = (float*)d_out;

  char* ws = (char*)d_ws;
  size_t off = 0;
  auto alloc = [&](size_t bytes) -> void* {
    void* p = ws + off;
    off = (off + bytes + 255) & ~(size_t)255;
    return p;
  };
  ushort* bufA = (ushort*)alloc((size_t)NN * 128 * 2);
  ushort* bufB = (ushort*)alloc((size_t)NN * 128 * 2);
  ushort* w1s = (ushort*)alloc(320 * 512 * 2);
  ushort* w2s = (ushort*)alloc(320 * 512 * 2);
  int* rowptr = (int*)alloc((NN + 1) * 4);
  int* cursor = (int*)alloc((size_t)NN * 4);
  int* eslot = (int*)alloc((size_t)EE * 4);
  int* bsums = (int*)alloc(1024 * 4);
  ushort* tabh = (ushort*)alloc(7552 * 2);
  int* xcode = (int*)alloc((size_t)NN * 4);
  float* stats = (float*)alloc((size_t)LL * 16 * 256 * 4);
  float* bnscale = (float*)alloc(LL * 128 * 4);
  float* bnshift = (float*)alloc(LL * 128 * 4);
  int* bhist = (int*)alloc((size_t)SCAN_NB * 256 * 4);
  int* bsums2 = (int*)alloc(1024 * 4);
  int4* ndesc = (int4*)alloc((size_t)NN * 16);

  hipMemsetAsync(cursor, 0, (size_t)NN * 4, stream);
  hipMemsetAsync(stats, 0, (size_t)LL * 16 * 256 * 4, stream);
  k_setup<<<SCAN_NB, 256, 0, stream>>>(W1, W2, w1s, w2s, ee1, ee2, at1, at2, tabh, xidx,
                                       xcode, out, bp);
  k_count<<<(EE + 255) / 256, 256, 0, stream>>>(eidx, cursor);
  k_scanA<<<SCAN_NB, 256, 0, stream>>>(cursor, rowptr, bsums);
  k_scanB<<<1, 1024, 0, stream>>>(bsums);
  k_scanC<<<SCAN_NB, 256, 0, stream>>>(rowptr, bsums);
  hipMemcpyAsync(cursor, rowptr, (size_t)NN * 4, hipMemcpyDeviceToDevice, stream);
  k_fill<<<(EE + 255) / 256, 256, 0, stream>>>(eidx, eattr, xcode, cursor, eslot);
  // degree-balanced node ordering (privatized counting sort, no global atomics)
  k_hist2<<<SCAN_NB, 256, 0, stream>>>(rowptr, bhist);
  k_hscanA<<<SCAN_NB, 256, 0, stream>>>(bhist, bsums2);
  k_scanB<<<1, 1024, 0, stream>>>(bsums2);
  k_hscanC<<<SCAN_NB, 256, 0, stream>>>(bhist, bsums2);
  k_dfill2<<<SCAN_NB, 256, 0, stream>>>(rowptr, xcode, bhist, ndesc);

  for (int l = 0; l < LL; ++l) {
    ushort* zo = (l & 1) ? bufB : bufA;
    const ushort* zi = (l & 1) ? bufA : bufB;  // raw z_{l-1}; unused for l==0
    k_layer<<<NN / 32, 256, 0, stream>>>((l == 0) ? bufA : zi, zo, ndesc, tabh, bnscale,
                                         bnshift, eslot, w1s, w2s, b1, b2,
                                         stats, l);
    k_bnparam<<<1, 128, 0, stream>>>(stats, gamma, beta, bnscale, bnshift, l);
  }
  k_pool<<<NN / 64, 256, 0, stream>>>(bufA, bnscale, bnshift, batch, Wp, out);
}

// Round 5
// 553.701 us; speedup vs baseline: 1.1120x; 1.0030x over previous
//
#include <hip/hip_runtime.h>

typedef unsigned int uint;
typedef unsigned short ushort;
typedef _Float16 f16_t;
typedef f16_t f16x8 __attribute__((ext_vector_type(8)));
typedef ushort ushort8 __attribute__((ext_vector_type(8)));
typedef float f32x4 __attribute__((ext_vector_type(4)));

#define NN 200000
#define EE 600000
#define LL 5
#define GG 2000
#define SCAN_NB 782  // ceil(NN/256); also 200192/256 for the bin-major hist scan

__device__ __forceinline__ ushort f2h(float f) {
  f16_t h = (f16_t)f;
  return __builtin_bit_cast(ushort, h);
}
__device__ __forceinline__ float h2f(ushort u) {
  return (float)__builtin_bit_cast(f16_t, u);
}
__device__ __forceinline__ float hlo(uint u) { return h2f((ushort)(u & 0xFFFFu)); }
__device__ __forceinline__ float hhi(uint u) { return h2f((ushort)(u >> 16)); }
__device__ __forceinline__ f16x8 ld8h(const uint4* p, int idx) {
  uint4 u = p[idx];
  return __builtin_bit_cast(f16x8, u);
}
// h = relu(z*sc+sh) in packed fp16 (v_pk_fma_f16 + v_pk_max_f16)
__device__ __forceinline__ f16x8 bnrelu8(f16x8 u, f16x8 sc, f16x8 sh) {
  f16x8 r = u * sc + sh;
#pragma unroll
  for (int j = 0; j < 8; ++j) r[j] = r[j] > (f16_t)0.f ? r[j] : (f16_t)0.f;
  return r;
}

// ---------------- merged setup: weight swizzle + fp16 tables + xcode + outinit ------
__global__ void k_setup(const float* __restrict__ W1, const float* __restrict__ W2,
                        ushort* __restrict__ w1s, ushort* __restrict__ w2s,
                        const float* __restrict__ ee1, const float* __restrict__ ee2,
                        const float* __restrict__ at1, const float* __restrict__ at2,
                        ushort* __restrict__ tabh, const int* __restrict__ xidx,
                        int* __restrict__ xcode, float* __restrict__ out,
                        const float* __restrict__ bp) {
  int i = blockIdx.x * 256 + threadIdx.x;
  if (i < 40960) {  // weight swizzle, B-frag 16x16x32 order
    int lane = i & 63;
    int f = i >> 6;
    bool isW2 = false;
    if (f >= 320) { f -= 320; isW2 = true; }
    int l = f >> 6, rem = f & 63;
    ushort8 o;
    if (!isW2) {
      int kt = rem >> 4, nt = rem & 15;
      int n = nt * 16 + (lane & 15);
      int kbase = kt * 32 + (lane >> 4) * 8;
#pragma unroll
      for (int j = 0; j < 8; ++j) o[j] = f2h(W1[l * 32768 + (kbase + j) * 256 + n]);
      *(ushort8*)(w1s + f * 512 + lane * 8) = o;
    } else {
      int kt = rem >> 3, nt = rem & 7;
      int n = nt * 16 + (lane & 15);
      int kbase = kt * 32 + (lane >> 4) * 8;
#pragma unroll
      for (int j = 0; j < 8; ++j) o[j] = f2h(W2[l * 32768 + (kbase + j) * 128 + n]);
      *(ushort8*)(w2s + f * 512 + lane * 8) = o;
    }
  }
  if (i < 5760) {  // comb (packed fp16)
    int l = i / 1152, rem = i % 1152;
    int ab = rem >> 7, c = rem & 127;
    int a = ab / 3, b = ab - a * 3;
    tabh[i] = f2h(ee1[(l * 6 + a) * 128 + c] + ee2[(l * 3 + b) * 128 + c]);
  } else if (i < 6400) {  // selfv
    int j = i - 5760;
    int l = j >> 7, c = j & 127;
    tabh[i] = f2h(ee1[(l * 6 + 4) * 128 + c] + ee2[(l * 3 + 0) * 128 + c]);
  } else if (i < 7552) {  // atomc
    int j = i - 6400;
    int ab = j >> 7, c = j & 127;
    int a = ab / 3, b = ab - a * 3;
    tabh[i] = f2h(at1[a * 128 + c] + at2[b * 128 + c]);
  }
  if (i < NN) xcode[i] = xidx[2 * i] * 3 + xidx[2 * i + 1];
  if (i < GG) out[i] = bp[0];
}

// ---------------- CSR build (dst is fixed across layers) ----------------
__global__ void k_count(const int* __restrict__ ei, int* __restrict__ counts) {
  int e = blockIdx.x * 256 + threadIdx.x;
  if (e < EE) atomicAdd(&counts[ei[EE + e]], 1);
}

__global__ void k_scanA(const int* __restrict__ counts, int* __restrict__ rowptr,
                        int* __restrict__ bsums) {
  __shared__ int sd[256];
  int tid = threadIdx.x;
  int g = blockIdx.x * 256 + tid;
  int v = (g < NN) ? counts[g] : 0;
  sd[tid] = v;
  __syncthreads();
  for (int o = 1; o < 256; o <<= 1) {
    int t = (tid >= o) ? sd[tid - o] : 0;
    __syncthreads();
    sd[tid] += t;
    __syncthreads();
  }
  if (g < NN) rowptr[g] = sd[tid] - v;
  if (tid == 255) bsums[blockIdx.x] = sd[tid];
}

__global__ void k_scanB(int* __restrict__ bsums) {
  __shared__ int sd[1024];
  int tid = threadIdx.x;
  int v = (tid < SCAN_NB) ? bsums[tid] : 0;
  sd[tid] = v;
  __syncthreads();
  for (int o = 1; o < 1024; o <<= 1) {
    int t = (tid >= o) ? sd[tid - o] : 0;
    __syncthreads();
    sd[tid] += t;
    __syncthreads();
  }
  if (tid < SCAN_NB) bsums[tid] = sd[tid] - v;
}

__global__ void k_scanC(int* __restrict__ rowptr, const int* __restrict__ bsums) {
  int g = blockIdx.x * 256 + threadIdx.x;
  if (g < NN) rowptr[g] += bsums[blockIdx.x];
  if (g == 0) rowptr[NN] = EE;
}

// pack src (18b) | a9 (4b) | xcode_src (4b)
__global__ void k_fill(const int* __restrict__ ei, const int* __restrict__ ea,
                       const int* __restrict__ xcode, int* __restrict__ cursor,
                       int* __restrict__ eslot) {
  int e = blockIdx.x * 256 + threadIdx.x;
  if (e < EE) {
    int dst = ei[EE + e];
    int src = ei[e];
    int a9 = ea[2 * e] * 3 + ea[2 * e + 1];
    int sc = xcode[src];
    int pos = atomicAdd(&cursor[dst], 1);
    eslot[pos] = src | (a9 << 18) | (sc << 22);
  }
}

// ---------------- degree-balanced node order (privatized counting sort) ----------
// R1 lesson: global atomicAdd-with-return on ~10 hot bins serialized 200k ops.
// Privatized: per-block LDS histograms -> bin-major global -> flat scan ->
// scatter with LDS-rank. No global atomics.
// R5: DESCENDING degree (bin = 255-d). Ascending put the heaviest blocks at the
// END of the grid -> drain tail on a few slow blocks. LPT order fixes that.
__global__ void k_hist2(const int* __restrict__ rowptr, int* __restrict__ bhist) {
  __shared__ int h[256];
  int tid = threadIdx.x;
  h[tid] = 0;
  __syncthreads();
  int n = blockIdx.x * 256 + tid;
  if (n < NN) {
    int d = rowptr[n + 1] - rowptr[n];
    if (d > 255) d = 255;
    atomicAdd(&h[255 - d], 1);
  }
  __syncthreads();
  bhist[tid * SCAN_NB + blockIdx.x] = h[tid];  // bin-major
}

// in-place exclusive scan over 782*256 = 200192 entries (exact multiple of 256)
__global__ void k_hscanA(int* __restrict__ data, int* __restrict__ bsums) {
  __shared__ int sd[256];
  int tid = threadIdx.x;
  int g = blockIdx.x * 256 + tid;
  int v = data[g];
  sd[tid] = v;
  __syncthreads();
  for (int o = 1; o < 256; o <<= 1) {
    int t = (tid >= o) ? sd[tid - o] : 0;
    __syncthreads();
    sd[tid] += t;
    __syncthreads();
  }
  data[g] = sd[tid] - v;
  if (tid == 255) bsums[blockIdx.x] = sd[tid];
}

__global__ void k_hscanC(int* __restrict__ data, const int* __restrict__ bsums) {
  int g = blockIdx.x * 256 + threadIdx.x;
  data[g] += bsums[blockIdx.x];
}

// ndesc[pos] = {node, rowstart, rowend, xcode[node]} in degree-DESC order
__global__ void k_dfill2(const int* __restrict__ rowptr, const int* __restrict__ xcode,
                         const int* __restrict__ bpos, int4* __restrict__ ndesc) {
  __shared__ int h[256];
  int tid = threadIdx.x;
  h[tid] = 0;
  __syncthreads();
  int n = blockIdx.x * 256 + tid;
  if (n < NN) {
    int s = rowptr[n], e = rowptr[n + 1];
    int d = e - s;
    if (d > 255) d = 255;
    int r = atomicAdd(&h[255 - d], 1);  // LDS rank within block
    int pos = bpos[(255 - d) * SCAN_NB + blockIdx.x] + r;
    ndesc[pos] = make_int4(n, s, e, xcode[n]);
  }
}

// ---------------- fused layer: packed-fp16 gather (BN affine inlined), fp16 MLP ----
// zin holds RAW z_{l-1}; per edge: p = relu_pk(z[src]*sc+sh); acc += p + comb.
// Block = 4 waves, 32 DEGREE-SORTED (desc) nodes, 16-lane sub-group per node.
// R5: BN params computed IN-BLOCK (redundantly) from the stats buffer -> removes
// the 5 serial 1-block k_bnparam launches from the inter-layer critical path.
// Cost: 16 coalesced 1KB loads of the L2-resident 16KB stats slice per block.
// Bit-identical numerics (same fp32 op order per channel as k_bnparam).
// R4 keeps: branchless x4 edge batching (VGPR stayed 44 though - compiler
// schedules min-pressure regardless; gather-ILP via source is a dead end).
__global__ __launch_bounds__(256, 5) void k_layer(
    const ushort* __restrict__ zin, ushort* __restrict__ zout,
    const int4* __restrict__ ndesc, const ushort* __restrict__ tabh,
    const float* __restrict__ stats_in, const float* __restrict__ gamma,
    const float* __restrict__ beta,
    const int* __restrict__ eslot,
    const ushort* __restrict__ w1s, const ushort* __restrict__ w2s,
    const float* __restrict__ b1, const float* __restrict__ b2,
    float* __restrict__ stats, int layer) {
  __shared__ __align__(16) ushort BUF[32 * 264];  // 16,896 B union
  __shared__ int4 ND[32];
  __shared__ float SS[256];   // per-channel sum/sumsq staging
  __shared__ float BNP[256];  // [0..127]=scale, [128..255]=shift
  ushort* AGG = BUF;   // 32 x 136 view (gather out / stage-1 in)
  ushort* T1 = BUF;    // 32 x 264 view (stage-1 out / stage-2 in)
  ushort* ldsZ = BUF;  // 32 x 136 view (stage-2 out / store staging)
  const int tid = threadIdx.x;
  const int w = tid >> 6, lane = tid & 63;
  const int ln16 = lane & 15, sub = lane >> 4;
  const int row0 = blockIdx.x * 32;

  if (tid < 32) ND[tid] = ndesc[row0 + tid];
  if (layer > 0) {
    // in-block BN param: column tid of stats slice summed over 16 partials
    const float* sb = stats_in + (size_t)(layer - 1) * 16 * 256;
    float a = 0.f;
#pragma unroll
    for (int cp = 0; cp < 16; ++cp) a += sb[cp * 256 + tid];
    SS[tid] = a;
    __syncthreads();
    if (tid < 128) {
      float mu = SS[tid] * (1.0f / NN);
      float var = SS[128 + tid] * (1.0f / NN) - mu * mu;
      float sc = gamma[(layer - 1) * 128 + tid] * rsqrtf(var + 1e-5f);
      BNP[tid] = sc;
      BNP[128 + tid] = beta[(layer - 1) * 128 + tid] - mu * sc;
    }
  }
  __syncthreads();

  // ---- gather phase: packed fp16, BN affine inlined ----
  const uint4* combH = (const uint4*)(tabh + (size_t)layer * 1152);
  const uint4* atomH = (const uint4*)(tabh + 6400);
  const uint4* selfH = (const uint4*)(tabh + 5760 + layer * 128);
  const uint4* h4 = (const uint4*)zin;
  f16x8 sf = ld8h(selfH, ln16);
  f16x8 scv = {}, shv = {};
  if (layer > 0) {
#pragma unroll
    for (int j = 0; j < 8; ++j) {
      scv[j] = (f16_t)BNP[ln16 * 8 + j];
      shv[j] = (f16_t)BNP[128 + ln16 * 8 + j];
    }
  }

#pragma unroll
  for (int grp = 0; grp < 2; ++grp) {
    const int4 nd = ND[w * 8 + grp * 4 + sub];
    const int n = nd.x;
    const int s = nd.y, e = nd.z;
    f16x8 acc;
    if (layer == 0) {
      acc = ld8h(atomH, nd.w * 16 + ln16) + sf;
    } else {
      acc = bnrelu8(ld8h(h4, (size_t)n * 16 + ln16), scv, shv) + sf;
    }
    for (int base = s; base < e; base += 16) {
      int m = e - base;
      if (m > 16) m = 16;
      int slot = (ln16 < m) ? eslot[base + ln16] : 0;
      int jfull = m & ~3;
      int j = 0;
      for (; j < jfull; j += 4) {
        // branchless depth-4 batch: all shfls, then all loads, then consume
        int sl0 = __shfl(slot, sub * 16 + j + 0, 64);
        int sl1 = __shfl(slot, sub * 16 + j + 1, 64);
        int sl2 = __shfl(slot, sub * 16 + j + 2, 64);
        int sl3 = __shfl(slot, sub * 16 + j + 3, 64);
        f16x8 p0, p1, p2, p3;
        if (layer == 0) {
          p0 = ld8h(atomH, ((sl0 >> 22) & 15) * 16 + ln16);
          p1 = ld8h(atomH, ((sl1 >> 22) & 15) * 16 + ln16);
          p2 = ld8h(atomH, ((sl2 >> 22) & 15) * 16 + ln16);
          p3 = ld8h(atomH, ((sl3 >> 22) & 15) * 16 + ln16);
        } else {
          p0 = ld8h(h4, (size_t)(sl0 & 0x3FFFF) * 16 + ln16);
          p1 = ld8h(h4, (size_t)(sl1 & 0x3FFFF) * 16 + ln16);
          p2 = ld8h(h4, (size_t)(sl2 & 0x3FFFF) * 16 + ln16);
          p3 = ld8h(h4, (size_t)(sl3 & 0x3FFFF) * 16 + ln16);
        }
        f16x8 c0 = ld8h(combH, ((sl0 >> 18) & 15) * 16 + ln16);
        f16x8 c1 = ld8h(combH, ((sl1 >> 18) & 15) * 16 + ln16);
        f16x8 c2 = ld8h(combH, ((sl2 >> 18) & 15) * 16 + ln16);
        f16x8 c3 = ld8h(combH, ((sl3 >> 18) & 15) * 16 + ln16);
        if (layer != 0) {
          p0 = bnrelu8(p0, scv, shv);
          p1 = bnrelu8(p1, scv, shv);
          p2 = bnrelu8(p2, scv, shv);
          p3 = bnrelu8(p3, scv, shv);
        }
        acc += p0 + c0;
        acc += p1 + c1;
        acc += p2 + c2;
        acc += p3 + c3;
      }
      for (; j < m; ++j) {
        int sl = __shfl(slot, sub * 16 + j, 64);
        f16x8 p0;
        if (layer == 0) {
          p0 = ld8h(atomH, ((sl >> 22) & 15) * 16 + ln16);
        } else {
          p0 = bnrelu8(ld8h(h4, (size_t)(sl & 0x3FFFF) * 16 + ln16), scv, shv);
        }
        f16x8 c0 = ld8h(combH, ((sl >> 18) & 15) * 16 + ln16);
        acc += p0 + c0;
      }
    }
    *(uint4*)&AGG[(w * 8 + grp * 4 + sub) * 136 + ln16 * 8] =
        __builtin_bit_cast(uint4, acc);
  }
  __syncthreads();

  // ---- MLP stage 1: acc = AGG @ W1, M=32, fp16; nt in pairs (smaller live set) ----
  const int lm = ln16, q = sub;
  f32x4 acc[2][4] = {};
  const ushort* w1b = w1s + layer * 64 * 512;
#pragma unroll
  for (int kt = 0; kt < 4; ++kt) {
    f16x8 af[2];
#pragma unroll
    for (int mt = 0; mt < 2; ++mt) {
      const ushort* p = AGG + (mt * 16 + lm) * 136 + kt * 32 + q * 8;
      af[mt] = __builtin_bit_cast(f16x8, *(const ushort8*)p);
    }
#pragma unroll
    for (int np = 0; np < 2; ++np) {
      f16x8 bf[2];
#pragma unroll
      for (int ni = 0; ni < 2; ++ni) {
        const ushort* p = w1b + (kt * 16 + w * 4 + np * 2 + ni) * 512 + lane * 8;
        bf[ni] = __builtin_bit_cast(f16x8, *(const ushort8*)p);
      }
#pragma unroll
      for (int mt = 0; mt < 2; ++mt)
#pragma unroll
        for (int ni = 0; ni < 2; ++ni)
          acc[mt][np * 2 + ni] = __builtin_amdgcn_mfma_f32_16x16x32_f16(
              af[mt], bf[ni], acc[mt][np * 2 + ni], 0, 0, 0);
    }
  }
  __syncthreads();  // AGG dead; T1 may now overwrite the union buffer
#pragma unroll
  for (int nt = 0; nt < 4; ++nt) {
    int n = w * 64 + nt * 16 + lm;
    float bias = b1[layer * 256 + n];
#pragma unroll
    for (int mt = 0; mt < 2; ++mt)
#pragma unroll
      for (int r = 0; r < 4; ++r) {
        float v = fmaxf(acc[mt][nt][r] + bias, 0.0f);
        T1[(mt * 16 + q * 4 + r) * 264 + n] = f2h(v);
      }
  }
  __syncthreads();

  // ---- MLP stage 2: z = T1 @ W2 + b2, + BN stats epilogue ----
  f32x4 acc2[2][2] = {};
  const ushort* w2b = w2s + layer * 64 * 512;
#pragma unroll
  for (int kt = 0; kt < 8; ++kt) {
    f16x8 af[2], bf[2];
#pragma unroll
    for (int mt = 0; mt < 2; ++mt) {
      const ushort* p = T1 + (mt * 16 + lm) * 264 + kt * 32 + q * 8;
      af[mt] = __builtin_bit_cast(f16x8, *(const ushort8*)p);
    }
#pragma unroll
    for (int nt = 0; nt < 2; ++nt) {
      const ushort* p = w2b + (kt * 8 + w * 2 + nt) * 512 + lane * 8;
      bf[nt] = __builtin_bit_cast(f16x8, *(const ushort8*)p);
    }
#pragma unroll
    for (int mt = 0; mt < 2; ++mt)
#pragma unroll
      for (int nt = 0; nt < 2; ++nt)
        acc2[mt][nt] = __builtin_amdgcn_mfma_f32_16x16x32_f16(af[mt], bf[nt], acc2[mt][nt], 0, 0, 0);
  }
  __syncthreads();  // T1 dead; ldsZ may now overwrite the union buffer
  float ssum[2], ssq[2];
#pragma unroll
  for (int nt = 0; nt < 2; ++nt) {
    int n = w * 32 + nt * 16 + lm;
    float bias = b2[layer * 128 + n];
    ssum[nt] = 0.f;
    ssq[nt] = 0.f;
#pragma unroll
    for (int mt = 0; mt < 2; ++mt)
#pragma unroll
      for (int r = 0; r < 4; ++r) {
        float v = acc2[mt][nt][r] + bias;
        ldsZ[(mt * 16 + q * 4 + r) * 136 + n] = f2h(v);
        ssum[nt] += v;
        ssq[nt] += v * v;
      }
    ssum[nt] += __shfl_xor(ssum[nt], 16, 64);
    ssum[nt] += __shfl_xor(ssum[nt], 32, 64);
    ssq[nt] += __shfl_xor(ssq[nt], 16, 64);
    ssq[nt] += __shfl_xor(ssq[nt], 32, 64);
  }
  if (lane < 16) {
    int cp = blockIdx.x & 15;
    float* sb = stats + (size_t)(layer * 16 + cp) * 256;
#pragma unroll
    for (int nt = 0; nt < 2; ++nt) {
      int col = w * 32 + nt * 16 + lane;
      atomicAdd(&sb[col], ssum[nt]);
      atomicAdd(&sb[128 + col], ssq[nt]);
    }
  }
  __syncthreads();
  uint* zo = (uint*)zout;
  for (int i = tid; i < 32 * 64; i += 256) {
    int row = i >> 6, cpx = i & 63;
    uint v = *(const uint*)&ldsZ[row * 136 + cpx * 2];
    zo[(size_t)ND[row].x * 64 + cpx] = v;
  }
}

// ---------------- pooling with segmented running sum (batch sorted) ----------------
// R5: BN-4 params computed in-block from stats (replaces last k_bnparam launch).
__global__ __launch_bounds__(256) void k_pool(const ushort* __restrict__ z,
                                              const float* __restrict__ stats,
                                              const float* __restrict__ gamma,
                                              const float* __restrict__ beta,
                                              const int* __restrict__ batch,
                                              const float* __restrict__ Wp,
                                              float* __restrict__ out) {
  __shared__ float SS[256];
  __shared__ float BNP[256];
  const int tid = threadIdx.x;
  const int w = tid >> 6, lane = tid & 63;
  const int nb = blockIdx.x * 64 + w * 16;
  {
    const float* sb = stats + (size_t)4 * 16 * 256;
    float a = 0.f;
#pragma unroll
    for (int cp = 0; cp < 16; ++cp) a += sb[cp * 256 + tid];
    SS[tid] = a;
    __syncthreads();
    if (tid < 128) {
      float mu = SS[tid] * (1.0f / NN);
      float var = SS[128 + tid] * (1.0f / NN) - mu * mu;
      float sc = gamma[4 * 128 + tid] * rsqrtf(var + 1e-5f);
      BNP[tid] = sc;
      BNP[128 + tid] = beta[4 * 128 + tid] - mu * sc;
    }
    __syncthreads();
  }
  float2 wp = ((const float2*)Wp)[lane];
  float2 scv = make_float2(BNP[2 * lane], BNP[2 * lane + 1]);
  float2 shv = make_float2(BNP[128 + 2 * lane], BNP[128 + 2 * lane + 1]);
  const uint* z32 = (const uint*)z;
  int bb = (lane < 16) ? batch[nb + lane] : 0;
  int curb = __shfl(bb, 0);
  float run = 0.f;
#pragma unroll
  for (int i = 0; i < 16; ++i) {
    int b = __shfl(bb, i);
    uint u = z32[(size_t)(nb + i) * 64 + lane];
    float dot = fmaf(hlo(u), scv.x, shv.x) * wp.x + fmaf(hhi(u), scv.y, shv.y) * wp.y;
#pragma unroll
    for (int off = 32; off > 0; off >>= 1) dot += __shfl_xor(dot, off, 64);
    if (b != curb) {
      if (lane == 0) atomicAdd(&out[curb], run);
      run = 0.f;
      curb = b;
    }
    run += dot;
  }
  if (lane == 0) atomicAdd(&out[curb], run);
}

extern "C" void kernel_launch(void* const* d_in, const int* in_sizes, int n_in,
                              void* d_out, int out_size, void* d_ws, size_t ws_size,
                              hipStream_t stream) {
  (void)in_sizes; (void)n_in; (void)out_size; (void)ws_size;
  const int* xidx = (const int*)d_in[0];
  const int* eidx = (const int*)d_in[1];
  const int* eattr = (const int*)d_in[2];
  const int* batch = (const int*)d_in[3];
  const float* at1 = (const float*)d_in[4];
  const float* at2 = (const float*)d_in[5];
  const float* ee1 = (const float*)d_in[6];
  const float* ee2 = (const float*)d_in[7];
  const float* W1 = (const float*)d_in[8];
  const float* b1 = (const float*)d_in[9];
  const float* W2 = (const float*)d_in[10];
  const float* b2 = (const float*)d_in[11];
  const float* gamma = (const float*)d_in[12];
  const float* beta = (const float*)d_in[13];
  const float* Wp = (const float*)d_in[14];
  const float* bp = (const float*)d_in[15];
  float* out = (float*)d_out;

  char* ws = (char*)d_ws;
  size_t off = 0;
  auto alloc = [&](size_t bytes) -> void* {
    void* p = ws + off;
    off = (off + bytes + 255) & ~(size_t)255;
    return p;
  };
  ushort* bufA = (ushort*)alloc((size_t)NN * 128 * 2);
  ushort* bufB = (ushort*)alloc((size_t)NN * 128 * 2);
  ushort* w1s = (ushort*)alloc(320 * 512 * 2);
  ushort* w2s = (ushort*)alloc(320 * 512 * 2);
  int* rowptr = (int*)alloc((NN + 1) * 4);
  int* cursor = (int*)alloc((size_t)NN * 4);
  int* eslot = (int*)alloc((size_t)EE * 4);
  int* bsums = (int*)alloc(1024 * 4);
  ushort* tabh = (ushort*)alloc(7552 * 2);
  int* xcode = (int*)alloc((size_t)NN * 4);
  float* stats = (float*)alloc((size_t)LL * 16 * 256 * 4);
  int* bhist = (int*)alloc((size_t)SCAN_NB * 256 * 4);
  int* bsums2 = (int*)alloc(1024 * 4);
  int4* ndesc = (int4*)alloc((size_t)NN * 16);

  hipMemsetAsync(cursor, 0, (size_t)NN * 4, stream);
  hipMemsetAsync(stats, 0, (size_t)LL * 16 * 256 * 4, stream);
  k_setup<<<SCAN_NB, 256, 0, stream>>>(W1, W2, w1s, w2s, ee1, ee2, at1, at2, tabh, xidx,
                                       xcode, out, bp);
  k_count<<<(EE + 255) / 256, 256, 0, stream>>>(eidx, cursor);
  k_scanA<<<SCAN_NB, 256, 0, stream>>>(cursor, rowptr, bsums);
  k_scanB<<<1, 1024, 0, stream>>>(bsums);
  k_scanC<<<SCAN_NB, 256, 0, stream>>>(rowptr, bsums);
  hipMemcpyAsync(cursor, rowptr, (size_t)NN * 4, hipMemcpyDeviceToDevice, stream);
  k_fill<<<(EE + 255) / 256, 256, 0, stream>>>(eidx, eattr, xcode, cursor, eslot);
  // degree-balanced node ordering (privatized counting sort, descending degree)
  k_hist2<<<SCAN_NB, 256, 0, stream>>>(rowptr, bhist);
  k_hscanA<<<SCAN_NB, 256, 0, stream>>>(bhist, bsums2);
  k_scanB<<<1, 1024, 0, stream>>>(bsums2);
  k_hscanC<<<SCAN_NB, 256, 0, stream>>>(bhist, bsums2);
  k_dfill2<<<SCAN_NB, 256, 0, stream>>>(rowptr, xcode, bhist, ndesc);

  for (int l = 0; l < LL; ++l) {
    ushort* zo = (l & 1) ? bufB : bufA;
    const ushort* zi = (l & 1) ? bufA : bufB;  // raw z_{l-1}; unused for l==0
    k_layer<<<NN / 32, 256, 0, stream>>>((l == 0) ? bufA : zi, zo, ndesc, tabh, stats,
                                         gamma, beta, eslot, w1s, w2s, b1, b2,
                                         stats, l);
  }
  k_pool<<<NN / 64, 256, 0, stream>>>(bufA, stats, gamma, beta, batch, Wp, out);
}

// Round 6
// 548.409 us; speedup vs baseline: 1.1227x; 1.0096x over previous
//
#include <hip/hip_runtime.h>

typedef unsigned int uint;
typedef unsigned short ushort;
typedef _Float16 f16_t;
typedef f16_t f16x8 __attribute__((ext_vector_type(8)));
typedef ushort ushort8 __attribute__((ext_vector_type(8)));
typedef float f32x4 __attribute__((ext_vector_type(4)));

#define NN 200000
#define EE 600000
#define LL 5
#define GG 2000
#define SCAN_NB 782  // ceil(NN/256); also 200192/256 for the bin-major hist scan

__device__ __forceinline__ ushort f2h(float f) {
  f16_t h = (f16_t)f;
  return __builtin_bit_cast(ushort, h);
}
__device__ __forceinline__ float h2f(ushort u) {
  return (float)__builtin_bit_cast(f16_t, u);
}
__device__ __forceinline__ float hlo(uint u) { return h2f((ushort)(u & 0xFFFFu)); }
__device__ __forceinline__ float hhi(uint u) { return h2f((ushort)(u >> 16)); }
__device__ __forceinline__ f16x8 ld8h(const uint4* p, int idx) {
  uint4 u = p[idx];
  return __builtin_bit_cast(f16x8, u);
}
// h = relu(z*sc+sh) in packed fp16 (v_pk_fma_f16 + v_pk_max_f16)
__device__ __forceinline__ f16x8 bnrelu8(f16x8 u, f16x8 sc, f16x8 sh) {
  f16x8 r = u * sc + sh;
#pragma unroll
  for (int j = 0; j < 8; ++j) r[j] = r[j] > (f16_t)0.f ? r[j] : (f16_t)0.f;
  return r;
}

// ---------------- merged setup: weight swizzle + fp16 tables + xcode + outinit ------
__global__ void k_setup(const float* __restrict__ W1, const float* __restrict__ W2,
                        ushort* __restrict__ w1s, ushort* __restrict__ w2s,
                        const float* __restrict__ ee1, const float* __restrict__ ee2,
                        const float* __restrict__ at1, const float* __restrict__ at2,
                        ushort* __restrict__ tabh, const int* __restrict__ xidx,
                        int* __restrict__ xcode, float* __restrict__ out,
                        const float* __restrict__ bp) {
  int i = blockIdx.x * 256 + threadIdx.x;
  if (i < 40960) {  // weight swizzle, B-frag 16x16x32 order
    int lane = i & 63;
    int f = i >> 6;
    bool isW2 = false;
    if (f >= 320) { f -= 320; isW2 = true; }
    int l = f >> 6, rem = f & 63;
    ushort8 o;
    if (!isW2) {
      int kt = rem >> 4, nt = rem & 15;
      int n = nt * 16 + (lane & 15);
      int kbase = kt * 32 + (lane >> 4) * 8;
#pragma unroll
      for (int j = 0; j < 8; ++j) o[j] = f2h(W1[l * 32768 + (kbase + j) * 256 + n]);
      *(ushort8*)(w1s + f * 512 + lane * 8) = o;
    } else {
      int kt = rem >> 3, nt = rem & 7;
      int n = nt * 16 + (lane & 15);
      int kbase = kt * 32 + (lane >> 4) * 8;
#pragma unroll
      for (int j = 0; j < 8; ++j) o[j] = f2h(W2[l * 32768 + (kbase + j) * 128 + n]);
      *(ushort8*)(w2s + f * 512 + lane * 8) = o;
    }
  }
  if (i < 5760) {  // comb (packed fp16)
    int l = i / 1152, rem = i % 1152;
    int ab = rem >> 7, c = rem & 127;
    int a = ab / 3, b = ab - a * 3;
    tabh[i] = f2h(ee1[(l * 6 + a) * 128 + c] + ee2[(l * 3 + b) * 128 + c]);
  } else if (i < 6400) {  // selfv
    int j = i - 5760;
    int l = j >> 7, c = j & 127;
    tabh[i] = f2h(ee1[(l * 6 + 4) * 128 + c] + ee2[(l * 3 + 0) * 128 + c]);
  } else if (i < 7552) {  // atomc
    int j = i - 6400;
    int ab = j >> 7, c = j & 127;
    int a = ab / 3, b = ab - a * 3;
    tabh[i] = f2h(at1[a * 128 + c] + at2[b * 128 + c]);
  }
  if (i < NN) xcode[i] = xidx[2 * i] * 3 + xidx[2 * i + 1];
  if (i < GG) out[i] = bp[0];
}

// ---------------- CSR build (dst is fixed across layers) ----------------
__global__ void k_count(const int* __restrict__ ei, int* __restrict__ counts) {
  int e = blockIdx.x * 256 + threadIdx.x;
  if (e < EE) atomicAdd(&counts[ei[EE + e]], 1);
}

__global__ void k_scanA(const int* __restrict__ counts, int* __restrict__ rowptr,
                        int* __restrict__ bsums) {
  __shared__ int sd[256];
  int tid = threadIdx.x;
  int g = blockIdx.x * 256 + tid;
  int v = (g < NN) ? counts[g] : 0;
  sd[tid] = v;
  __syncthreads();
  for (int o = 1; o < 256; o <<= 1) {
    int t = (tid >= o) ? sd[tid - o] : 0;
    __syncthreads();
    sd[tid] += t;
    __syncthreads();
  }
  if (g < NN) rowptr[g] = sd[tid] - v;
  if (tid == 255) bsums[blockIdx.x] = sd[tid];
}

__global__ void k_scanB(int* __restrict__ bsums) {
  __shared__ int sd[1024];
  int tid = threadIdx.x;
  int v = (tid < SCAN_NB) ? bsums[tid] : 0;
  sd[tid] = v;
  __syncthreads();
  for (int o = 1; o < 1024; o <<= 1) {
    int t = (tid >= o) ? sd[tid - o] : 0;
    __syncthreads();
    sd[tid] += t;
    __syncthreads();
  }
  if (tid < SCAN_NB) bsums[tid] = sd[tid] - v;
}

__global__ void k_scanC(int* __restrict__ rowptr, const int* __restrict__ bsums) {
  int g = blockIdx.x * 256 + threadIdx.x;
  if (g < NN) rowptr[g] += bsums[blockIdx.x];
  if (g == 0) rowptr[NN] = EE;
}

// pack src (18b) | a9 (4b) | xcode_src (4b)
__global__ void k_fill(const int* __restrict__ ei, const int* __restrict__ ea,
                       const int* __restrict__ xcode, int* __restrict__ cursor,
                       int* __restrict__ eslot) {
  int e = blockIdx.x * 256 + threadIdx.x;
  if (e < EE) {
    int dst = ei[EE + e];
    int src = ei[e];
    int a9 = ea[2 * e] * 3 + ea[2 * e + 1];
    int sc = xcode[src];
    int pos = atomicAdd(&cursor[dst], 1);
    eslot[pos] = src | (a9 << 18) | (sc << 22);
  }
}

// ---------------- degree-balanced node order (privatized counting sort) ----------
// R1 lesson: global atomicAdd-with-return on ~10 hot bins serialized 200k ops.
// Privatized: per-block LDS histograms -> bin-major global -> flat scan ->
// scatter with LDS-rank. No global atomics. Descending degree (LPT order).
__global__ void k_hist2(const int* __restrict__ rowptr, int* __restrict__ bhist) {
  __shared__ int h[256];
  int tid = threadIdx.x;
  h[tid] = 0;
  __syncthreads();
  int n = blockIdx.x * 256 + tid;
  if (n < NN) {
    int d = rowptr[n + 1] - rowptr[n];
    if (d > 255) d = 255;
    atomicAdd(&h[255 - d], 1);
  }
  __syncthreads();
  bhist[tid * SCAN_NB + blockIdx.x] = h[tid];  // bin-major
}

// in-place exclusive scan over 782*256 = 200192 entries (exact multiple of 256)
__global__ void k_hscanA(int* __restrict__ data, int* __restrict__ bsums) {
  __shared__ int sd[256];
  int tid = threadIdx.x;
  int g = blockIdx.x * 256 + tid;
  int v = data[g];
  sd[tid] = v;
  __syncthreads();
  for (int o = 1; o < 256; o <<= 1) {
    int t = (tid >= o) ? sd[tid - o] : 0;
    __syncthreads();
    sd[tid] += t;
    __syncthreads();
  }
  data[g] = sd[tid] - v;
  if (tid == 255) bsums[blockIdx.x] = sd[tid];
}

__global__ void k_hscanC(int* __restrict__ data, const int* __restrict__ bsums) {
  int g = blockIdx.x * 256 + threadIdx.x;
  data[g] += bsums[blockIdx.x];
}

// ndesc[pos] = {node, rowstart, rowend, xcode[node]} in degree-DESC order
__global__ void k_dfill2(const int* __restrict__ rowptr, const int* __restrict__ xcode,
                         const int* __restrict__ bpos, int4* __restrict__ ndesc) {
  __shared__ int h[256];
  int tid = threadIdx.x;
  h[tid] = 0;
  __syncthreads();
  int n = blockIdx.x * 256 + tid;
  if (n < NN) {
    int s = rowptr[n], e = rowptr[n + 1];
    int d = e - s;
    if (d > 255) d = 255;
    int r = atomicAdd(&h[255 - d], 1);  // LDS rank within block
    int pos = bpos[(255 - d) * SCAN_NB + blockIdx.x] + r;
    ndesc[pos] = make_int4(n, s, e, xcode[n]);
  }
}

// ---------------- fused layer: packed-fp16 gather (BN affine inlined), fp16 MLP ----
// zin holds RAW z_{l-1}; per edge: p = relu_pk(z[src]*sc+sh); acc += p + comb.
// Block = 4 waves, 32 DEGREE-SORTED (desc) nodes, 16-lane sub-group per node.
// R6: launch_bounds (256,5) -> (256,8). Counters across R2-R5: every pipe <40%,
// occupancy pinned at ~48% (the (256,5) cap is 62.5%). VGPR=44 <= 64 and LDS
// 19.5KB x 8 = 155.6KB <= 160KB, so 8 blocks/CU are physically feasible.
// Latency-bound gather -> attack with TLP (2x resident waves), since source-ILP
// attempts (R3 predicated x8, R4 branchless x4) were defeated by the compiler's
// min-pressure scheduling (VGPR stayed 44 both times).
__global__ __launch_bounds__(256, 8) void k_layer(
    const ushort* __restrict__ zin, ushort* __restrict__ zout,
    const int4* __restrict__ ndesc, const ushort* __restrict__ tabh,
    const float* __restrict__ stats_in, const float* __restrict__ gamma,
    const float* __restrict__ beta,
    const int* __restrict__ eslot,
    const ushort* __restrict__ w1s, const ushort* __restrict__ w2s,
    const float* __restrict__ b1, const float* __restrict__ b2,
    float* __restrict__ stats, int layer) {
  __shared__ __align__(16) ushort BUF[32 * 264];  // 16,896 B union
  __shared__ int4 ND[32];
  __shared__ float SS[256];   // per-channel sum/sumsq staging
  __shared__ float BNP[256];  // [0..127]=scale, [128..255]=shift
  ushort* AGG = BUF;   // 32 x 136 view (gather out / stage-1 in)
  ushort* T1 = BUF;    // 32 x 264 view (stage-1 out / stage-2 in)
  ushort* ldsZ = BUF;  // 32 x 136 view (stage-2 out / store staging)
  const int tid = threadIdx.x;
  const int w = tid >> 6, lane = tid & 63;
  const int ln16 = lane & 15, sub = lane >> 4;
  const int row0 = blockIdx.x * 32;

  if (tid < 32) ND[tid] = ndesc[row0 + tid];
  if (layer > 0) {
    // in-block BN param: column tid of stats slice summed over 16 partials
    const float* sb = stats_in + (size_t)(layer - 1) * 16 * 256;
    float a = 0.f;
#pragma unroll
    for (int cp = 0; cp < 16; ++cp) a += sb[cp * 256 + tid];
    SS[tid] = a;
    __syncthreads();
    if (tid < 128) {
      float mu = SS[tid] * (1.0f / NN);
      float var = SS[128 + tid] * (1.0f / NN) - mu * mu;
      float sc = gamma[(layer - 1) * 128 + tid] * rsqrtf(var + 1e-5f);
      BNP[tid] = sc;
      BNP[128 + tid] = beta[(layer - 1) * 128 + tid] - mu * sc;
    }
  }
  __syncthreads();

  // ---- gather phase: packed fp16, BN affine inlined ----
  const uint4* combH = (const uint4*)(tabh + (size_t)layer * 1152);
  const uint4* atomH = (const uint4*)(tabh + 6400);
  const uint4* selfH = (const uint4*)(tabh + 5760 + layer * 128);
  const uint4* h4 = (const uint4*)zin;
  f16x8 sf = ld8h(selfH, ln16);
  f16x8 scv = {}, shv = {};
  if (layer > 0) {
#pragma unroll
    for (int j = 0; j < 8; ++j) {
      scv[j] = (f16_t)BNP[ln16 * 8 + j];
      shv[j] = (f16_t)BNP[128 + ln16 * 8 + j];
    }
  }

#pragma unroll
  for (int grp = 0; grp < 2; ++grp) {
    const int4 nd = ND[w * 8 + grp * 4 + sub];
    const int n = nd.x;
    const int s = nd.y, e = nd.z;
    f16x8 acc;
    if (layer == 0) {
      acc = ld8h(atomH, nd.w * 16 + ln16) + sf;
    } else {
      acc = bnrelu8(ld8h(h4, (size_t)n * 16 + ln16), scv, shv) + sf;
    }
    for (int base = s; base < e; base += 16) {
      int m = e - base;
      if (m > 16) m = 16;
      int slot = (ln16 < m) ? eslot[base + ln16] : 0;
      int jfull = m & ~3;
      int j = 0;
      for (; j < jfull; j += 4) {
        // branchless depth-4 batch: all shfls, then all loads, then consume
        int sl0 = __shfl(slot, sub * 16 + j + 0, 64);
        int sl1 = __shfl(slot, sub * 16 + j + 1, 64);
        int sl2 = __shfl(slot, sub * 16 + j + 2, 64);
        int sl3 = __shfl(slot, sub * 16 + j + 3, 64);
        f16x8 p0, p1, p2, p3;
        if (layer == 0) {
          p0 = ld8h(atomH, ((sl0 >> 22) & 15) * 16 + ln16);
          p1 = ld8h(atomH, ((sl1 >> 22) & 15) * 16 + ln16);
          p2 = ld8h(atomH, ((sl2 >> 22) & 15) * 16 + ln16);
          p3 = ld8h(atomH, ((sl3 >> 22) & 15) * 16 + ln16);
        } else {
          p0 = ld8h(h4, (size_t)(sl0 & 0x3FFFF) * 16 + ln16);
          p1 = ld8h(h4, (size_t)(sl1 & 0x3FFFF) * 16 + ln16);
          p2 = ld8h(h4, (size_t)(sl2 & 0x3FFFF) * 16 + ln16);
          p3 = ld8h(h4, (size_t)(sl3 & 0x3FFFF) * 16 + ln16);
        }
        f16x8 c0 = ld8h(combH, ((sl0 >> 18) & 15) * 16 + ln16);
        f16x8 c1 = ld8h(combH, ((sl1 >> 18) & 15) * 16 + ln16);
        f16x8 c2 = ld8h(combH, ((sl2 >> 18) & 15) * 16 + ln16);
        f16x8 c3 = ld8h(combH, ((sl3 >> 18) & 15) * 16 + ln16);
        if (layer != 0) {
          p0 = bnrelu8(p0, scv, shv);
          p1 = bnrelu8(p1, scv, shv);
          p2 = bnrelu8(p2, scv, shv);
          p3 = bnrelu8(p3, scv, shv);
        }
        acc += p0 + c0;
        acc += p1 + c1;
        acc += p2 + c2;
        acc += p3 + c3;
      }
      for (; j < m; ++j) {
        int sl = __shfl(slot, sub * 16 + j, 64);
        f16x8 p0;
        if (layer == 0) {
          p0 = ld8h(atomH, ((sl >> 22) & 15) * 16 + ln16);
        } else {
          p0 = bnrelu8(ld8h(h4, (size_t)(sl & 0x3FFFF) * 16 + ln16), scv, shv);
        }
        f16x8 c0 = ld8h(combH, ((sl >> 18) & 15) * 16 + ln16);
        acc += p0 + c0;
      }
    }
    *(uint4*)&AGG[(w * 8 + grp * 4 + sub) * 136 + ln16 * 8] =
        __builtin_bit_cast(uint4, acc);
  }
  __syncthreads();

  // ---- MLP stage 1: acc = AGG @ W1, M=32, fp16; nt in pairs (smaller live set) ----
  const int lm = ln16, q = sub;
  f32x4 acc[2][4] = {};
  const ushort* w1b = w1s + layer * 64 * 512;
#pragma unroll
  for (int kt = 0; kt < 4; ++kt) {
    f16x8 af[2];
#pragma unroll
    for (int mt = 0; mt < 2; ++mt) {
      const ushort* p = AGG + (mt * 16 + lm) * 136 + kt * 32 + q * 8;
      af[mt] = __builtin_bit_cast(f16x8, *(const ushort8*)p);
    }
#pragma unroll
    for (int np = 0; np < 2; ++np) {
      f16x8 bf[2];
#pragma unroll
      for (int ni = 0; ni < 2; ++ni) {
        const ushort* p = w1b + (kt * 16 + w * 4 + np * 2 + ni) * 512 + lane * 8;
        bf[ni] = __builtin_bit_cast(f16x8, *(const ushort8*)p);
      }
#pragma unroll
      for (int mt = 0; mt < 2; ++mt)
#pragma unroll
        for (int ni = 0; ni < 2; ++ni)
          acc[mt][np * 2 + ni] = __builtin_amdgcn_mfma_f32_16x16x32_f16(
              af[mt], bf[ni], acc[mt][np * 2 + ni], 0, 0, 0);
    }
  }
  __syncthreads();  // AGG dead; T1 may now overwrite the union buffer
#pragma unroll
  for (int nt = 0; nt < 4; ++nt) {
    int n = w * 64 + nt * 16 + lm;
    float bias = b1[layer * 256 + n];
#pragma unroll
    for (int mt = 0; mt < 2; ++mt)
#pragma unroll
      for (int r = 0; r < 4; ++r) {
        float v = fmaxf(acc[mt][nt][r] + bias, 0.0f);
        T1[(mt * 16 + q * 4 + r) * 264 + n] = f2h(v);
      }
  }
  __syncthreads();

  // ---- MLP stage 2: z = T1 @ W2 + b2, + BN stats epilogue ----
  f32x4 acc2[2][2] = {};
  const ushort* w2b = w2s + layer * 64 * 512;
#pragma unroll
  for (int kt = 0; kt < 8; ++kt) {
    f16x8 af[2], bf[2];
#pragma unroll
    for (int mt = 0; mt < 2; ++mt) {
      const ushort* p = T1 + (mt * 16 + lm) * 264 + kt * 32 + q * 8;
      af[mt] = __builtin_bit_cast(f16x8, *(const ushort8*)p);
    }
#pragma unroll
    for (int nt = 0; nt < 2; ++nt) {
      const ushort* p = w2b + (kt * 8 + w * 2 + nt) * 512 + lane * 8;
      bf[nt] = __builtin_bit_cast(f16x8, *(const ushort8*)p);
    }
#pragma unroll
    for (int mt = 0; mt < 2; ++mt)
#pragma unroll
      for (int nt = 0; nt < 2; ++nt)
        acc2[mt][nt] = __builtin_amdgcn_mfma_f32_16x16x32_f16(af[mt], bf[nt], acc2[mt][nt], 0, 0, 0);
  }
  __syncthreads();  // T1 dead; ldsZ may now overwrite the union buffer
  float ssum[2], ssq[2];
#pragma unroll
  for (int nt = 0; nt < 2; ++nt) {
    int n = w * 32 + nt * 16 + lm;
    float bias = b2[layer * 128 + n];
    ssum[nt] = 0.f;
    ssq[nt] = 0.f;
#pragma unroll
    for (int mt = 0; mt < 2; ++mt)
#pragma unroll
      for (int r = 0; r < 4; ++r) {
        float v = acc2[mt][nt][r] + bias;
        ldsZ[(mt * 16 + q * 4 + r) * 136 + n] = f2h(v);
        ssum[nt] += v;
        ssq[nt] += v * v;
      }
    ssum[nt] += __shfl_xor(ssum[nt], 16, 64);
    ssum[nt] += __shfl_xor(ssum[nt], 32, 64);
    ssq[nt] += __shfl_xor(ssq[nt], 16, 64);
    ssq[nt] += __shfl_xor(ssq[nt], 32, 64);
  }
  if (lane < 16) {
    int cp = blockIdx.x & 15;
    float* sb = stats + (size_t)(layer * 16 + cp) * 256;
#pragma unroll
    for (int nt = 0; nt < 2; ++nt) {
      int col = w * 32 + nt * 16 + lane;
      atomicAdd(&sb[col], ssum[nt]);
      atomicAdd(&sb[128 + col], ssq[nt]);
    }
  }
  __syncthreads();
  uint* zo = (uint*)zout;
  for (int i = tid; i < 32 * 64; i += 256) {
    int row = i >> 6, cpx = i & 63;
    uint v = *(const uint*)&ldsZ[row * 136 + cpx * 2];
    zo[(size_t)ND[row].x * 64 + cpx] = v;
  }
}

// ---------------- pooling with segmented running sum (batch sorted) ----------------
// BN-4 params computed in-block from stats (replaces last k_bnparam launch).
__global__ __launch_bounds__(256) void k_pool(const ushort* __restrict__ z,
                                              const float* __restrict__ stats,
                                              const float* __restrict__ gamma,
                                              const float* __restrict__ beta,
                                              const int* __restrict__ batch,
                                              const float* __restrict__ Wp,
                                              float* __restrict__ out) {
  __shared__ float SS[256];
  __shared__ float BNP[256];
  const int tid = threadIdx.x;
  const int w = tid >> 6, lane = tid & 63;
  const int nb = blockIdx.x * 64 + w * 16;
  {
    const float* sb = stats + (size_t)4 * 16 * 256;
    float a = 0.f;
#pragma unroll
    for (int cp = 0; cp < 16; ++cp) a += sb[cp * 256 + tid];
    SS[tid] = a;
    __syncthreads();
    if (tid < 128) {
      float mu = SS[tid] * (1.0f / NN);
      float var = SS[128 + tid] * (1.0f / NN) - mu * mu;
      float sc = gamma[4 * 128 + tid] * rsqrtf(var + 1e-5f);
      BNP[tid] = sc;
      BNP[128 + tid] = beta[4 * 128 + tid] - mu * sc;
    }
    __syncthreads();
  }
  float2 wp = ((const float2*)Wp)[lane];
  float2 scv = make_float2(BNP[2 * lane], BNP[2 * lane + 1]);
  float2 shv = make_float2(BNP[128 + 2 * lane], BNP[128 + 2 * lane + 1]);
  const uint* z32 = (const uint*)z;
  int bb = (lane < 16) ? batch[nb + lane] : 0;
  int curb = __shfl(bb, 0);
  float run = 0.f;
#pragma unroll
  for (int i = 0; i < 16; ++i) {
    int b = __shfl(bb, i);
    uint u = z32[(size_t)(nb + i) * 64 + lane];
    float dot = fmaf(hlo(u), scv.x, shv.x) * wp.x + fmaf(hhi(u), scv.y, shv.y) * wp.y;
#pragma unroll
    for (int off = 32; off > 0; off >>= 1) dot += __shfl_xor(dot, off, 64);
    if (b != curb) {
      if (lane == 0) atomicAdd(&out[curb], run);
      run = 0.f;
      curb = b;
    }
    run += dot;
  }
  if (lane == 0) atomicAdd(&out[curb], run);
}

extern "C" void kernel_launch(void* const* d_in, const int* in_sizes, int n_in,
                              void* d_out, int out_size, void* d_ws, size_t ws_size,
                              hipStream_t stream) {
  (void)in_sizes; (void)n_in; (void)out_size; (void)ws_size;
  const int* xidx = (const int*)d_in[0];
  const int* eidx = (const int*)d_in[1];
  const int* eattr = (const int*)d_in[2];
  const int* batch = (const int*)d_in[3];
  const float* at1 = (const float*)d_in[4];
  const float* at2 = (const float*)d_in[5];
  const float* ee1 = (const float*)d_in[6];
  const float* ee2 = (const float*)d_in[7];
  const float* W1 = (const float*)d_in[8];
  const float* b1 = (const float*)d_in[9];
  const float* W2 = (const float*)d_in[10];
  const float* b2 = (const float*)d_in[11];
  const float* gamma = (const float*)d_in[12];
  const float* beta = (const float*)d_in[13];
  const float* Wp = (const float*)d_in[14];
  const float* bp = (const float*)d_in[15];
  float* out = (float*)d_out;

  char* ws = (char*)d_ws;
  size_t off = 0;
  auto alloc = [&](size_t bytes) -> void* {
    void* p = ws + off;
    off = (off + bytes + 255) & ~(size_t)255;
    return p;
  };
  ushort* bufA = (ushort*)alloc((size_t)NN * 128 * 2);
  ushort* bufB = (ushort*)alloc((size_t)NN * 128 * 2);
  ushort* w1s = (ushort*)alloc(320 * 512 * 2);
  ushort* w2s = (ushort*)alloc(320 * 512 * 2);
  int* rowptr = (int*)alloc((NN + 1) * 4);
  int* cursor = (int*)alloc((size_t)NN * 4);
  int* eslot = (int*)alloc((size_t)EE * 4);
  int* bsums = (int*)alloc(1024 * 4);
  ushort* tabh = (ushort*)alloc(7552 * 2);
  int* xcode = (int*)alloc((size_t)NN * 4);
  float* stats = (float*)alloc((size_t)LL * 16 * 256 * 4);
  int* bhist = (int*)alloc((size_t)SCAN_NB * 256 * 4);
  int* bsums2 = (int*)alloc(1024 * 4);
  int4* ndesc = (int4*)alloc((size_t)NN * 16);

  hipMemsetAsync(cursor, 0, (size_t)NN * 4, stream);
  hipMemsetAsync(stats, 0, (size_t)LL * 16 * 256 * 4, stream);
  k_setup<<<SCAN_NB, 256, 0, stream>>>(W1, W2, w1s, w2s, ee1, ee2, at1, at2, tabh, xidx,
                                       xcode, out, bp);
  k_count<<<(EE + 255) / 256, 256, 0, stream>>>(eidx, cursor);
  k_scanA<<<SCAN_NB, 256, 0, stream>>>(cursor, rowptr, bsums);
  k_scanB<<<1, 1024, 0, stream>>>(bsums);
  k_scanC<<<SCAN_NB, 256, 0, stream>>>(rowptr, bsums);
  hipMemcpyAsync(cursor, rowptr, (size_t)NN * 4, hipMemcpyDeviceToDevice, stream);
  k_fill<<<(EE + 255) / 256, 256, 0, stream>>>(eidx, eattr, xcode, cursor, eslot);
  // degree-balanced node ordering (privatized counting sort, descending degree)
  k_hist2<<<SCAN_NB, 256, 0, stream>>>(rowptr, bhist);
  k_hscanA<<<SCAN_NB, 256, 0, stream>>>(bhist, bsums2);
  k_scanB<<<1, 1024, 0, stream>>>(bsums2);
  k_hscanC<<<SCAN_NB, 256, 0, stream>>>(bhist, bsums2);
  k_dfill2<<<SCAN_NB, 256, 0, stream>>>(rowptr, xcode, bhist, ndesc);

  for (int l = 0; l < LL; ++l) {
    ushort* zo = (l & 1) ? bufB : bufA;
    const ushort* zi = (l & 1) ? bufA : bufB;  // raw z_{l-1}; unused for l==0
    k_layer<<<NN / 32, 256, 0, stream>>>((l == 0) ? bufA : zi, zo, ndesc, tabh, stats,
                                         gamma, beta, eslot, w1s, w2s, b1, b2,
                                         stats, l);
  }
  k_pool<<<NN / 64, 256, 0, stream>>>(bufA, stats, gamma, beta, batch, Wp, out);
}

// Round 7
// 519.117 us; speedup vs baseline: 1.1861x; 1.0564x over previous
//
#include <hip/hip_runtime.h>

typedef unsigned int uint;
typedef unsigned short ushort;
typedef _Float16 f16_t;
typedef f16_t f16x8 __attribute__((ext_vector_type(8)));
typedef ushort ushort8 __attribute__((ext_vector_type(8)));
typedef float f32x4 __attribute__((ext_vector_type(4)));

#define NN 200000
#define EE 600000
#define LL 5
#define GG 2000
#define SCAN_NB 782  // ceil(NN/256); also 200192/256 for the bin-major hist scan

__device__ __forceinline__ ushort f2h(float f) {
  f16_t h = (f16_t)f;
  return __builtin_bit_cast(ushort, h);
}
__device__ __forceinline__ float h2f(ushort u) {
  return (float)__builtin_bit_cast(f16_t, u);
}
__device__ __forceinline__ float hlo(uint u) { return h2f((ushort)(u & 0xFFFFu)); }
__device__ __forceinline__ float hhi(uint u) { return h2f((ushort)(u >> 16)); }
__device__ __forceinline__ f16x8 ld8h(const uint4* p, int idx) {
  uint4 u = p[idx];
  return __builtin_bit_cast(f16x8, u);
}
// h = relu(z*sc+sh) in packed fp16 (v_pk_fma_f16 + v_pk_max_f16)
__device__ __forceinline__ f16x8 bnrelu8(f16x8 u, f16x8 sc, f16x8 sh) {
  f16x8 r = u * sc + sh;
#pragma unroll
  for (int j = 0; j < 8; ++j) r[j] = r[j] > (f16_t)0.f ? r[j] : (f16_t)0.f;
  return r;
}

// ---------------- merged setup: weight swizzle + fp16 tables + xcode + outinit ------
__global__ void k_setup(const float* __restrict__ W1, const float* __restrict__ W2,
                        ushort* __restrict__ w1s, ushort* __restrict__ w2s,
                        const float* __restrict__ ee1, const float* __restrict__ ee2,
                        const float* __restrict__ at1, const float* __restrict__ at2,
                        ushort* __restrict__ tabh, const int* __restrict__ xidx,
                        int* __restrict__ xcode, float* __restrict__ out,
                        const float* __restrict__ bp) {
  int i = blockIdx.x * 256 + threadIdx.x;
  if (i < 40960) {  // weight swizzle, B-frag 16x16x32 order
    int lane = i & 63;
    int f = i >> 6;
    bool isW2 = false;
    if (f >= 320) { f -= 320; isW2 = true; }
    int l = f >> 6, rem = f & 63;
    ushort8 o;
    if (!isW2) {
      int kt = rem >> 4, nt = rem & 15;
      int n = nt * 16 + (lane & 15);
      int kbase = kt * 32 + (lane >> 4) * 8;
#pragma unroll
      for (int j = 0; j < 8; ++j) o[j] = f2h(W1[l * 32768 + (kbase + j) * 256 + n]);
      *(ushort8*)(w1s + f * 512 + lane * 8) = o;
    } else {
      int kt = rem >> 3, nt = rem & 7;
      int n = nt * 16 + (lane & 15);
      int kbase = kt * 32 + (lane >> 4) * 8;
#pragma unroll
      for (int j = 0; j < 8; ++j) o[j] = f2h(W2[l * 32768 + (kbase + j) * 128 + n]);
      *(ushort8*)(w2s + f * 512 + lane * 8) = o;
    }
  }
  if (i < 5760) {  // comb (packed fp16)
    int l = i / 1152, rem = i % 1152;
    int ab = rem >> 7, c = rem & 127;
    int a = ab / 3, b = ab - a * 3;
    tabh[i] = f2h(ee1[(l * 6 + a) * 128 + c] + ee2[(l * 3 + b) * 128 + c]);
  } else if (i < 6400) {  // selfv
    int j = i - 5760;
    int l = j >> 7, c = j & 127;
    tabh[i] = f2h(ee1[(l * 6 + 4) * 128 + c] + ee2[(l * 3 + 0) * 128 + c]);
  } else if (i < 7552) {  // atomc
    int j = i - 6400;
    int ab = j >> 7, c = j & 127;
    int a = ab / 3, b = ab - a * 3;
    tabh[i] = f2h(at1[a * 128 + c] + at2[b * 128 + c]);
  }
  if (i < NN) xcode[i] = xidx[2 * i] * 3 + xidx[2 * i + 1];
  if (i < GG) out[i] = bp[0];
}

// ---------------- CSR build (dst is fixed across layers) ----------------
__global__ void k_count(const int* __restrict__ ei, int* __restrict__ counts) {
  int e = blockIdx.x * 256 + threadIdx.x;
  if (e < EE) atomicAdd(&counts[ei[EE + e]], 1);
}

__global__ void k_scanA(const int* __restrict__ counts, int* __restrict__ rowptr,
                        int* __restrict__ bsums) {
  __shared__ int sd[256];
  int tid = threadIdx.x;
  int g = blockIdx.x * 256 + tid;
  int v = (g < NN) ? counts[g] : 0;
  sd[tid] = v;
  __syncthreads();
  for (int o = 1; o < 256; o <<= 1) {
    int t = (tid >= o) ? sd[tid - o] : 0;
    __syncthreads();
    sd[tid] += t;
    __syncthreads();
  }
  if (g < NN) rowptr[g] = sd[tid] - v;
  if (tid == 255) bsums[blockIdx.x] = sd[tid];
}

__global__ void k_scanB(int* __restrict__ bsums) {
  __shared__ int sd[1024];
  int tid = threadIdx.x;
  int v = (tid < SCAN_NB) ? bsums[tid] : 0;
  sd[tid] = v;
  __syncthreads();
  for (int o = 1; o < 1024; o <<= 1) {
    int t = (tid >= o) ? sd[tid - o] : 0;
    __syncthreads();
    sd[tid] += t;
    __syncthreads();
  }
  if (tid < SCAN_NB) bsums[tid] = sd[tid] - v;
}

__global__ void k_scanC(int* __restrict__ rowptr, const int* __restrict__ bsums) {
  int g = blockIdx.x * 256 + threadIdx.x;
  if (g < NN) rowptr[g] += bsums[blockIdx.x];
  if (g == 0) rowptr[NN] = EE;
}

// pack src (18b) | a9 (4b) | xcode_src (4b)
__global__ void k_fill(const int* __restrict__ ei, const int* __restrict__ ea,
                       const int* __restrict__ xcode, int* __restrict__ cursor,
                       int* __restrict__ eslot) {
  int e = blockIdx.x * 256 + threadIdx.x;
  if (e < EE) {
    int dst = ei[EE + e];
    int src = ei[e];
    int a9 = ea[2 * e] * 3 + ea[2 * e + 1];
    int sc = xcode[src];
    int pos = atomicAdd(&cursor[dst], 1);
    eslot[pos] = src | (a9 << 18) | (sc << 22);
  }
}

// ---------------- degree-balanced node order (privatized counting sort) ----------
// R1 lesson: global atomicAdd-with-return on ~10 hot bins serialized 200k ops.
// Privatized: per-block LDS histograms -> bin-major global -> flat scan ->
// scatter with LDS-rank. No global atomics. Descending degree (LPT order).
__global__ void k_hist2(const int* __restrict__ rowptr, int* __restrict__ bhist) {
  __shared__ int h[256];
  int tid = threadIdx.x;
  h[tid] = 0;
  __syncthreads();
  int n = blockIdx.x * 256 + tid;
  if (n < NN) {
    int d = rowptr[n + 1] - rowptr[n];
    if (d > 255) d = 255;
    atomicAdd(&h[255 - d], 1);
  }
  __syncthreads();
  bhist[tid * SCAN_NB + blockIdx.x] = h[tid];  // bin-major
}

// in-place exclusive scan over 782*256 = 200192 entries (exact multiple of 256)
__global__ void k_hscanA(int* __restrict__ data, int* __restrict__ bsums) {
  __shared__ int sd[256];
  int tid = threadIdx.x;
  int g = blockIdx.x * 256 + tid;
  int v = data[g];
  sd[tid] = v;
  __syncthreads();
  for (int o = 1; o < 256; o <<= 1) {
    int t = (tid >= o) ? sd[tid - o] : 0;
    __syncthreads();
    sd[tid] += t;
    __syncthreads();
  }
  data[g] = sd[tid] - v;
  if (tid == 255) bsums[blockIdx.x] = sd[tid];
}

__global__ void k_hscanC(int* __restrict__ data, const int* __restrict__ bsums) {
  int g = blockIdx.x * 256 + threadIdx.x;
  data[g] += bsums[blockIdx.x];
}

// ndesc[pos] = {node, rowstart, rowend, xcode[node]} in degree-DESC order
__global__ void k_dfill2(const int* __restrict__ rowptr, const int* __restrict__ xcode,
                         const int* __restrict__ bpos, int4* __restrict__ ndesc) {
  __shared__ int h[256];
  int tid = threadIdx.x;
  h[tid] = 0;
  __syncthreads();
  int n = blockIdx.x * 256 + tid;
  if (n < NN) {
    int s = rowptr[n], e = rowptr[n + 1];
    int d = e - s;
    if (d > 255) d = 255;
    int r = atomicAdd(&h[255 - d], 1);  // LDS rank within block
    int pos = bpos[(255 - d) * SCAN_NB + blockIdx.x] + r;
    ndesc[pos] = make_int4(n, s, e, xcode[n]);
  }
}

// ---------------- fused layer: packed-fp16 gather (BN affine inlined), fp16 MLP ----
// R7: M=64 per block (512 threads, 8 waves). R6 evidence: block-completion
// throughput fixed (~3.5us/CU) while per-block latency grew with residency ->
// saturated shared queue, i.e. per-XCD L2 bandwidth, not wave slots. Dominant
// L2 term was weight re-reads (6250 blocks x 128KB = 800MB/layer, invisible in
// FETCH_SIZE since L2-resident). Doubling M halves weight traffic (400MB),
// stats preamble (50MB) and stats atomics (0.8M) per layer.
// launch_bounds (512,6): VGPR budget ~85 fits stage-1 live set (~71), no spill;
// LDS 36.9KB -> 3 blocks/CU (24 waves, 75% cap).
__global__ __launch_bounds__(512, 6) void k_layer(
    const ushort* __restrict__ zin, ushort* __restrict__ zout,
    const int4* __restrict__ ndesc, const ushort* __restrict__ tabh,
    const float* __restrict__ stats_in, const float* __restrict__ gamma,
    const float* __restrict__ beta,
    const int* __restrict__ eslot,
    const ushort* __restrict__ w1s, const ushort* __restrict__ w2s,
    const float* __restrict__ b1, const float* __restrict__ b2,
    float* __restrict__ stats, int layer) {
  __shared__ __align__(16) ushort BUF[64 * 264];  // 33,792 B union
  __shared__ int4 ND[64];
  __shared__ float SS[256];   // per-channel sum/sumsq staging
  __shared__ float BNP[256];  // [0..127]=scale, [128..255]=shift
  ushort* AGG = BUF;   // 64 x 136 view (gather out / stage-1 in)
  ushort* T1 = BUF;    // 64 x 264 view (stage-1 out / stage-2 in)
  ushort* ldsZ = BUF;  // 64 x 136 view (stage-2 out / store staging)
  const int tid = threadIdx.x;
  const int w = tid >> 6, lane = tid & 63;
  const int ln16 = lane & 15, sub = lane >> 4;
  const int row0 = blockIdx.x * 64;

  if (tid < 64) ND[tid] = ndesc[row0 + tid];
  if (layer > 0) {
    // in-block BN param: column tid of stats slice summed over 16 partials
    if (tid < 256) {
      const float* sb = stats_in + (size_t)(layer - 1) * 16 * 256;
      float a = 0.f;
#pragma unroll
      for (int cp = 0; cp < 16; ++cp) a += sb[cp * 256 + tid];
      SS[tid] = a;
    }
    __syncthreads();
    if (tid < 128) {
      float mu = SS[tid] * (1.0f / NN);
      float var = SS[128 + tid] * (1.0f / NN) - mu * mu;
      float sc = gamma[(layer - 1) * 128 + tid] * rsqrtf(var + 1e-5f);
      BNP[tid] = sc;
      BNP[128 + tid] = beta[(layer - 1) * 128 + tid] - mu * sc;
    }
  }
  __syncthreads();

  // ---- gather phase: packed fp16, BN affine inlined ----
  const uint4* combH = (const uint4*)(tabh + (size_t)layer * 1152);
  const uint4* atomH = (const uint4*)(tabh + 6400);
  const uint4* selfH = (const uint4*)(tabh + 5760 + layer * 128);
  const uint4* h4 = (const uint4*)zin;
  f16x8 sf = ld8h(selfH, ln16);
  f16x8 scv = {}, shv = {};
  if (layer > 0) {
#pragma unroll
    for (int j = 0; j < 8; ++j) {
      scv[j] = (f16_t)BNP[ln16 * 8 + j];
      shv[j] = (f16_t)BNP[128 + ln16 * 8 + j];
    }
  }

#pragma unroll
  for (int grp = 0; grp < 2; ++grp) {
    const int4 nd = ND[w * 8 + grp * 4 + sub];
    const int n = nd.x;
    const int s = nd.y, e = nd.z;
    f16x8 acc;
    if (layer == 0) {
      acc = ld8h(atomH, nd.w * 16 + ln16) + sf;
    } else {
      acc = bnrelu8(ld8h(h4, (size_t)n * 16 + ln16), scv, shv) + sf;
    }
    for (int base = s; base < e; base += 16) {
      int m = e - base;
      if (m > 16) m = 16;
      int slot = (ln16 < m) ? eslot[base + ln16] : 0;
      int jfull = m & ~3;
      int j = 0;
      for (; j < jfull; j += 4) {
        // branchless depth-4 batch: all shfls, then all loads, then consume
        int sl0 = __shfl(slot, sub * 16 + j + 0, 64);
        int sl1 = __shfl(slot, sub * 16 + j + 1, 64);
        int sl2 = __shfl(slot, sub * 16 + j + 2, 64);
        int sl3 = __shfl(slot, sub * 16 + j + 3, 64);
        f16x8 p0, p1, p2, p3;
        if (layer == 0) {
          p0 = ld8h(atomH, ((sl0 >> 22) & 15) * 16 + ln16);
          p1 = ld8h(atomH, ((sl1 >> 22) & 15) * 16 + ln16);
          p2 = ld8h(atomH, ((sl2 >> 22) & 15) * 16 + ln16);
          p3 = ld8h(atomH, ((sl3 >> 22) & 15) * 16 + ln16);
        } else {
          p0 = ld8h(h4, (size_t)(sl0 & 0x3FFFF) * 16 + ln16);
          p1 = ld8h(h4, (size_t)(sl1 & 0x3FFFF) * 16 + ln16);
          p2 = ld8h(h4, (size_t)(sl2 & 0x3FFFF) * 16 + ln16);
          p3 = ld8h(h4, (size_t)(sl3 & 0x3FFFF) * 16 + ln16);
        }
        f16x8 c0 = ld8h(combH, ((sl0 >> 18) & 15) * 16 + ln16);
        f16x8 c1 = ld8h(combH, ((sl1 >> 18) & 15) * 16 + ln16);
        f16x8 c2 = ld8h(combH, ((sl2 >> 18) & 15) * 16 + ln16);
        f16x8 c3 = ld8h(combH, ((sl3 >> 18) & 15) * 16 + ln16);
        if (layer != 0) {
          p0 = bnrelu8(p0, scv, shv);
          p1 = bnrelu8(p1, scv, shv);
          p2 = bnrelu8(p2, scv, shv);
          p3 = bnrelu8(p3, scv, shv);
        }
        acc += p0 + c0;
        acc += p1 + c1;
        acc += p2 + c2;
        acc += p3 + c3;
      }
      for (; j < m; ++j) {
        int sl = __shfl(slot, sub * 16 + j, 64);
        f16x8 p0;
        if (layer == 0) {
          p0 = ld8h(atomH, ((sl >> 22) & 15) * 16 + ln16);
        } else {
          p0 = bnrelu8(ld8h(h4, (size_t)(sl & 0x3FFFF) * 16 + ln16), scv, shv);
        }
        f16x8 c0 = ld8h(combH, ((sl >> 18) & 15) * 16 + ln16);
        acc += p0 + c0;
      }
    }
    *(uint4*)&AGG[(w * 8 + grp * 4 + sub) * 136 + ln16 * 8] =
        __builtin_bit_cast(uint4, acc);
  }
  __syncthreads();

  // ---- MLP stage 1: acc = AGG @ W1, M=64; wave w covers n in [32w, 32w+32) ----
  const int lm = ln16, q = sub;
  f32x4 acc[4][2] = {};
  const ushort* w1b = w1s + layer * 64 * 512;
#pragma unroll
  for (int kt = 0; kt < 4; ++kt) {
    f16x8 af[4];
#pragma unroll
    for (int mt = 0; mt < 4; ++mt) {
      const ushort* p = AGG + (mt * 16 + lm) * 136 + kt * 32 + q * 8;
      af[mt] = __builtin_bit_cast(f16x8, *(const ushort8*)p);
    }
    f16x8 bf[2];
#pragma unroll
    for (int ni = 0; ni < 2; ++ni) {
      const ushort* p = w1b + (kt * 16 + w * 2 + ni) * 512 + lane * 8;
      bf[ni] = __builtin_bit_cast(f16x8, *(const ushort8*)p);
    }
#pragma unroll
    for (int mt = 0; mt < 4; ++mt)
#pragma unroll
      for (int ni = 0; ni < 2; ++ni)
        acc[mt][ni] = __builtin_amdgcn_mfma_f32_16x16x32_f16(
            af[mt], bf[ni], acc[mt][ni], 0, 0, 0);
  }
  __syncthreads();  // AGG dead; T1 may now overwrite the union buffer
#pragma unroll
  for (int nt = 0; nt < 2; ++nt) {
    int n = w * 32 + nt * 16 + lm;
    float bias = b1[layer * 256 + n];
#pragma unroll
    for (int mt = 0; mt < 4; ++mt)
#pragma unroll
      for (int r = 0; r < 4; ++r) {
        float v = fmaxf(acc[mt][nt][r] + bias, 0.0f);
        T1[(mt * 16 + q * 4 + r) * 264 + n] = f2h(v);
      }
  }
  __syncthreads();

  // ---- MLP stage 2: z = T1 @ W2 + b2; wave w covers n in [16w, 16w+16) ----
  f32x4 acc2[4] = {};
  const ushort* w2b = w2s + layer * 64 * 512;
#pragma unroll
  for (int kt = 0; kt < 8; ++kt) {
    f16x8 af[4], bf;
#pragma unroll
    for (int mt = 0; mt < 4; ++mt) {
      const ushort* p = T1 + (mt * 16 + lm) * 264 + kt * 32 + q * 8;
      af[mt] = __builtin_bit_cast(f16x8, *(const ushort8*)p);
    }
    {
      const ushort* p = w2b + (kt * 8 + w) * 512 + lane * 8;
      bf = __builtin_bit_cast(f16x8, *(const ushort8*)p);
    }
#pragma unroll
    for (int mt = 0; mt < 4; ++mt)
      acc2[mt] = __builtin_amdgcn_mfma_f32_16x16x32_f16(af[mt], bf, acc2[mt], 0, 0, 0);
  }
  __syncthreads();  // T1 dead; ldsZ may now overwrite the union buffer
  float ssum = 0.f, ssq = 0.f;
  {
    int n = w * 16 + lm;
    float bias = b2[layer * 128 + n];
#pragma unroll
    for (int mt = 0; mt < 4; ++mt)
#pragma unroll
      for (int r = 0; r < 4; ++r) {
        float v = acc2[mt][r] + bias;
        ldsZ[(mt * 16 + q * 4 + r) * 136 + n] = f2h(v);
        ssum += v;
        ssq += v * v;
      }
    ssum += __shfl_xor(ssum, 16, 64);
    ssum += __shfl_xor(ssum, 32, 64);
    ssq += __shfl_xor(ssq, 16, 64);
    ssq += __shfl_xor(ssq, 32, 64);
  }
  if (lane < 16) {
    int cp = blockIdx.x & 15;
    float* sb = stats + (size_t)(layer * 16 + cp) * 256;
    int col = w * 16 + lane;
    atomicAdd(&sb[col], ssum);
    atomicAdd(&sb[128 + col], ssq);
  }
  __syncthreads();
  uint* zo = (uint*)zout;
  for (int i = tid; i < 64 * 64; i += 512) {
    int row = i >> 6, cpx = i & 63;
    uint v = *(const uint*)&ldsZ[row * 136 + cpx * 2];
    zo[(size_t)ND[row].x * 64 + cpx] = v;
  }
}

// ---------------- pooling with segmented running sum (batch sorted) ----------------
// BN-4 params computed in-block from stats (replaces last k_bnparam launch).
__global__ __launch_bounds__(256) void k_pool(const ushort* __restrict__ z,
                                              const float* __restrict__ stats,
                                              const float* __restrict__ gamma,
                                              const float* __restrict__ beta,
                                              const int* __restrict__ batch,
                                              const float* __restrict__ Wp,
                                              float* __restrict__ out) {
  __shared__ float SS[256];
  __shared__ float BNP[256];
  const int tid = threadIdx.x;
  const int w = tid >> 6, lane = tid & 63;
  const int nb = blockIdx.x * 64 + w * 16;
  {
    const float* sb = stats + (size_t)4 * 16 * 256;
    float a = 0.f;
#pragma unroll
    for (int cp = 0; cp < 16; ++cp) a += sb[cp * 256 + tid];
    SS[tid] = a;
    __syncthreads();
    if (tid < 128) {
      float mu = SS[tid] * (1.0f / NN);
      float var = SS[128 + tid] * (1.0f / NN) - mu * mu;
      float sc = gamma[4 * 128 + tid] * rsqrtf(var + 1e-5f);
      BNP[tid] = sc;
      BNP[128 + tid] = beta[4 * 128 + tid] - mu * sc;
    }
    __syncthreads();
  }
  float2 wp = ((const float2*)Wp)[lane];
  float2 scv = make_float2(BNP[2 * lane], BNP[2 * lane + 1]);
  float2 shv = make_float2(BNP[128 + 2 * lane], BNP[128 + 2 * lane + 1]);
  const uint* z32 = (const uint*)z;
  int bb = (lane < 16) ? batch[nb + lane] : 0;
  int curb = __shfl(bb, 0);
  float run = 0.f;
#pragma unroll
  for (int i = 0; i < 16; ++i) {
    int b = __shfl(bb, i);
    uint u = z32[(size_t)(nb + i) * 64 + lane];
    float dot = fmaf(hlo(u), scv.x, shv.x) * wp.x + fmaf(hhi(u), scv.y, shv.y) * wp.y;
#pragma unroll
    for (int off = 32; off > 0; off >>= 1) dot += __shfl_xor(dot, off, 64);
    if (b != curb) {
      if (lane == 0) atomicAdd(&out[curb], run);
      run = 0.f;
      curb = b;
    }
    run += dot;
  }
  if (lane == 0) atomicAdd(&out[curb], run);
}

extern "C" void kernel_launch(void* const* d_in, const int* in_sizes, int n_in,
                              void* d_out, int out_size, void* d_ws, size_t ws_size,
                              hipStream_t stream) {
  (void)in_sizes; (void)n_in; (void)out_size; (void)ws_size;
  const int* xidx = (const int*)d_in[0];
  const int* eidx = (const int*)d_in[1];
  const int* eattr = (const int*)d_in[2];
  const int* batch = (const int*)d_in[3];
  const float* at1 = (const float*)d_in[4];
  const float* at2 = (const float*)d_in[5];
  const float* ee1 = (const float*)d_in[6];
  const float* ee2 = (const float*)d_in[7];
  const float* W1 = (const float*)d_in[8];
  const float* b1 = (const float*)d_in[9];
  const float* W2 = (const float*)d_in[10];
  const float* b2 = (const float*)d_in[11];
  const float* gamma = (const float*)d_in[12];
  const float* beta = (const float*)d_in[13];
  const float* Wp = (const float*)d_in[14];
  const float* bp = (const float*)d_in[15];
  float* out = (float*)d_out;

  char* ws = (char*)d_ws;
  size_t off = 0;
  auto alloc = [&](size_t bytes) -> void* {
    void* p = ws + off;
    off = (off + bytes + 255) & ~(size_t)255;
    return p;
  };
  ushort* bufA = (ushort*)alloc((size_t)NN * 128 * 2);
  ushort* bufB = (ushort*)alloc((size_t)NN * 128 * 2);
  ushort* w1s = (ushort*)alloc(320 * 512 * 2);
  ushort* w2s = (ushort*)alloc(320 * 512 * 2);
  int* rowptr = (int*)alloc((NN + 1) * 4);
  int* cursor = (int*)alloc((size_t)NN * 4);
  int* eslot = (int*)alloc((size_t)EE * 4);
  int* bsums = (int*)alloc(1024 * 4);
  ushort* tabh = (ushort*)alloc(7552 * 2);
  int* xcode = (int*)alloc((size_t)NN * 4);
  float* stats = (float*)alloc((size_t)LL * 16 * 256 * 4);
  int* bhist = (int*)alloc((size_t)SCAN_NB * 256 * 4);
  int* bsums2 = (int*)alloc(1024 * 4);
  int4* ndesc = (int4*)alloc((size_t)NN * 16);

  hipMemsetAsync(cursor, 0, (size_t)NN * 4, stream);
  hipMemsetAsync(stats, 0, (size_t)LL * 16 * 256 * 4, stream);
  k_setup<<<SCAN_NB, 256, 0, stream>>>(W1, W2, w1s, w2s, ee1, ee2, at1, at2, tabh, xidx,
                                       xcode, out, bp);
  k_count<<<(EE + 255) / 256, 256, 0, stream>>>(eidx, cursor);
  k_scanA<<<SCAN_NB, 256, 0, stream>>>(cursor, rowptr, bsums);
  k_scanB<<<1, 1024, 0, stream>>>(bsums);
  k_scanC<<<SCAN_NB, 256, 0, stream>>>(rowptr, bsums);
  hipMemcpyAsync(cursor, rowptr, (size_t)NN * 4, hipMemcpyDeviceToDevice, stream);
  k_fill<<<(EE + 255) / 256, 256, 0, stream>>>(eidx, eattr, xcode, cursor, eslot);
  // degree-balanced node ordering (privatized counting sort, descending degree)
  k_hist2<<<SCAN_NB, 256, 0, stream>>>(rowptr, bhist);
  k_hscanA<<<SCAN_NB, 256, 0, stream>>>(bhist, bsums2);
  k_scanB<<<1, 1024, 0, stream>>>(bsums2);
  k_hscanC<<<SCAN_NB, 256, 0, stream>>>(bhist, bsums2);
  k_dfill2<<<SCAN_NB, 256, 0, stream>>>(rowptr, xcode, bhist, ndesc);

  for (int l = 0; l < LL; ++l) {
    ushort* zo = (l & 1) ? bufB : bufA;
    const ushort* zi = (l & 1) ? bufA : bufB;  // raw z_{l-1}; unused for l==0
    k_layer<<<NN / 64, 512, 0, stream>>>((l == 0) ? bufA : zi, zo, ndesc, tabh, stats,
                                         gamma, beta, eslot, w1s, w2s, b1, b2,
                                         stats, l);
  }
  k_pool<<<NN / 64, 256, 0, stream>>>(bufA, stats, gamma, beta, batch, Wp, out);
}